// Round 1
// baseline (1532.758 us; speedup 1.0000x reference)
//
#include <hip/hip_runtime.h>
#include <hip/hip_bf16.h>

typedef float f32x4 __attribute__((ext_vector_type(4)));
typedef unsigned short u16x8 __attribute__((ext_vector_type(8)));

static __device__ __forceinline__ void mfma16(f32x4& c, const u16x8& a, const u16x8& b) {
    asm("v_mfma_f32_16x16x32_bf16 %0, %1, %2, %0" : "+v"(c) : "v"(a), "v"(b));
}

static __device__ __forceinline__ unsigned short f2bf(float f) {
    __hip_bfloat16 h = __float2bfloat16(f);
    return *reinterpret_cast<unsigned short*>(&h);
}

// ---------------- graph prep ----------------

__global__ __launch_bounds__(256) void k_deg_count(const int* __restrict__ src, const int* __restrict__ dst,
                                                   const float* __restrict__ ew, float* deg, int* cnt, int E) {
    int e = blockIdx.x * 256 + threadIdx.x;
    if (e >= E) return;
    int s = src[e], d = dst[e];
    float w = (s == d) ? 0.f : ew[e];
    atomicAdd(&deg[s], w);
    atomicAdd(&cnt[d], 1);
}

__global__ __launch_bounds__(256) void k_dis(float* deg, int N) {
    int i = blockIdx.x * 256 + threadIdx.x;
    if (i >= N) return;
    float d = deg[i];
    deg[i] = (d > 0.f) ? rsqrtf(d) : 0.f;
}

__global__ __launch_bounds__(1024) void k_blocksum(const int* __restrict__ cnt, int* bsum, int N) {
    __shared__ int sd[1024];
    int i = blockIdx.x * 1024 + threadIdx.x;
    sd[threadIdx.x] = (i < N) ? cnt[i] : 0;
    __syncthreads();
    for (int s = 512; s > 0; s >>= 1) {
        if (threadIdx.x < s) sd[threadIdx.x] += sd[threadIdx.x + s];
        __syncthreads();
    }
    if (threadIdx.x == 0) bsum[blockIdx.x] = sd[0];
}

__global__ __launch_bounds__(128) void k_scan_bsum(int* bsum, int nb) {
    __shared__ int sd[128];
    int t = threadIdx.x;
    int v = (t < nb) ? bsum[t] : 0;
    sd[t] = v;
    __syncthreads();
    for (int d = 1; d < 128; d <<= 1) {
        int x = (t >= d) ? sd[t - d] : 0;
        __syncthreads();
        sd[t] += x;
        __syncthreads();
    }
    if (t < nb) bsum[t] = sd[t] - v;  // exclusive block offsets
}

__global__ __launch_bounds__(1024) void k_scan(const int* __restrict__ cnt, const int* __restrict__ bsum,
                                               int* rowp, int* cur, int N) {
    __shared__ int sd[1024];
    int i = blockIdx.x * 1024 + threadIdx.x;
    int v = (i < N) ? cnt[i] : 0;
    sd[threadIdx.x] = v;
    __syncthreads();
    for (int d = 1; d < 1024; d <<= 1) {
        int x = (threadIdx.x >= d) ? sd[threadIdx.x - d] : 0;
        __syncthreads();
        sd[threadIdx.x] += x;
        __syncthreads();
    }
    if (i < N) {
        int excl = sd[threadIdx.x] - v + bsum[blockIdx.x];
        rowp[i] = excl;
        cur[i]  = excl;
    }
}

// pack (src, w_hat) per CSR slot
__global__ __launch_bounds__(256) void k_build_csr(const int* __restrict__ src, const int* __restrict__ dst,
                                                   const float* __restrict__ ew, const float* __restrict__ dis,
                                                   int* cur, int2* __restrict__ pack, int E) {
    int e = blockIdx.x * 256 + threadIdx.x;
    if (e >= E) return;
    int s = src[e], d = dst[e];
    float w = (s == d) ? 0.f : ew[e];
    float wh = -dis[s] * w * dis[d];
    int pos = atomicAdd(&cur[d], 1);
    int2 p;
    p.x = s;
    p.y = __float_as_int(wh);
    pack[pos] = p;
}

// ---------------- feature prep ----------------

// hb[n][0..159] = [x | lap_pe | 0pad] as bf16
__global__ __launch_bounds__(256) void k_concat(const float* __restrict__ x, const float* __restrict__ pe,
                                                unsigned short* __restrict__ hb, int N) {
    int i = blockIdx.x * 256 + threadIdx.x;
    if (i >= N * 160) return;
    int n = i / 160, k = i - n * 160;
    float v = (k < 128) ? x[n * 128 + k] : (k < 144 ? pe[n * 16 + (k - 128)] : 0.f);
    hb[i] = f2bf(v);
}

// AT[sel][n][kk] = A_sel[kk][n] (transposed, bf16), A0=W0-W2, A1=W1-3W3, A2=2W2, A3=4W3
__global__ __launch_bounds__(256) void k_combine(const float* __restrict__ W, unsigned short* __restrict__ AT,
                                                 int D, int KPAD) {
    int i = blockIdx.x * 256 + threadIdx.x;
    int tot = 4 * 128 * KPAD;
    if (i >= tot) return;
    int sel = i / (128 * KPAD);
    int rem = i - sel * 128 * KPAD;
    int n = rem / KPAD;
    int kk = rem - n * KPAD;
    float v = 0.f;
    if (kk < D) {
        if (sel == 0)      v = W[(0 * D + kk) * 128 + n] - W[(2 * D + kk) * 128 + n];
        else if (sel == 1) v = W[(1 * D + kk) * 128 + n] - 3.f * W[(3 * D + kk) * 128 + n];
        else if (sel == 2) v = 2.f * W[(2 * D + kk) * 128 + n];
        else               v = 4.f * W[(3 * D + kk) * 128 + n];
    }
    AT[i] = f2bf(v);
}

__global__ __launch_bounds__(256) void k_headsT(const float* __restrict__ Wmu, const float* __restrict__ Wlv,
                                                unsigned short* __restrict__ AT) {
    int i = blockIdx.x * 256 + threadIdx.x;
    if (i >= 128 * 128) return;
    int n = i >> 7, kk = i & 127;
    float v = (n < 64) ? Wmu[kk * 64 + n] : Wlv[kk * 64 + (n - 64)];
    AT[i] = f2bf(v);
}

// ---------------- GEMM: C[M,128] = hb[M,KPAD](bf16) @ AT^T, MFMA 16x16x32 ----------------
// Bt is [128][KPAD] = B^T (row n holds column n of B). BM=128, BN=64 (grid.y=2).

template <int KPAD, int MODE>
__global__ __launch_bounds__(256) void k_gemm(const unsigned short* __restrict__ Abf,
                                              const unsigned short* __restrict__ Bt,
                                              float* __restrict__ out,
                                              const float* __restrict__ bmu, const float* __restrict__ blv,
                                              int N) {
    constexpr int LP = KPAD + 8;  // padded LDS pitch (breaks bank-conflict stride)
    __shared__ __align__(16) unsigned short As[128 * LP];
    __shared__ __align__(16) unsigned short Bs[64 * LP];
    const int tid = threadIdx.x;
    const int row0 = blockIdx.x * 128;
    const int bn = blockIdx.y;

    {   // stage A tile (128 x KPAD), row-clamped
        constexpr int TOT = 128 * KPAD;
        for (int c = tid * 8; c < TOT; c += 256 * 8) {
            int r = c / KPAD;
            int k = c - r * KPAD;
            int gr = row0 + r;
            if (gr > N - 1) gr = N - 1;
            u16x8 v = *reinterpret_cast<const u16x8*>(&Abf[gr * KPAD + k]);
            *reinterpret_cast<u16x8*>(&As[r * LP + k]) = v;
        }
    }
    {   // stage B tile (64 x KPAD) from Bt rows [bn*64, bn*64+64)
        constexpr int TOT = 64 * KPAD;
        for (int c = tid * 8; c < TOT; c += 256 * 8) {
            int r = c / KPAD;
            int k = c - r * KPAD;
            u16x8 v = *reinterpret_cast<const u16x8*>(&Bt[(bn * 64 + r) * KPAD + k]);
            *reinterpret_cast<u16x8*>(&Bs[r * LP + k]) = v;
        }
    }
    __syncthreads();

    const int wave = tid >> 6, lane = tid & 63;
    const int wm = wave >> 1, wn = wave & 1;
    const int lr = lane & 15, lg = lane >> 4;

    f32x4 acc[4][2];
#pragma unroll
    for (int i = 0; i < 4; i++)
#pragma unroll
        for (int j = 0; j < 2; j++) acc[i][j] = (f32x4){0.f, 0.f, 0.f, 0.f};

    // fence: ensure zero-init movs land >=8 cycles before first MFMA reads srcC
    asm volatile("s_nop 7"
                 : "+v"(acc[0][0]), "+v"(acc[0][1]), "+v"(acc[1][0]), "+v"(acc[1][1]),
                   "+v"(acc[2][0]), "+v"(acc[2][1]), "+v"(acc[3][0]), "+v"(acc[3][1]));

    constexpr int KS = KPAD / 32;
#pragma unroll
    for (int ks = 0; ks < KS; ks++) {
        u16x8 a[4], b[2];
#pragma unroll
        for (int fm = 0; fm < 4; fm++)
            a[fm] = *reinterpret_cast<const u16x8*>(&As[(wm * 64 + fm * 16 + lr) * LP + ks * 32 + lg * 8]);
#pragma unroll
        for (int fn = 0; fn < 2; fn++)
            b[fn] = *reinterpret_cast<const u16x8*>(&Bs[(wn * 32 + fn * 16 + lr) * LP + ks * 32 + lg * 8]);
#pragma unroll
        for (int fm = 0; fm < 4; fm++)
#pragma unroll
            for (int fn = 0; fn < 2; fn++) mfma16(acc[fm][fn], a[fm], b[fn]);
    }

    // fence: MFMA write -> VALU/VMEM read hazard (24 cycles)
    asm volatile("s_nop 7\n\ts_nop 7\n\ts_nop 7"
                 : "+v"(acc[0][0]), "+v"(acc[0][1]), "+v"(acc[1][0]), "+v"(acc[1][1]),
                   "+v"(acc[2][0]), "+v"(acc[2][1]), "+v"(acc[3][0]), "+v"(acc[3][1]));

#pragma unroll
    for (int fm = 0; fm < 4; fm++)
#pragma unroll
        for (int fn = 0; fn < 2; fn++)
#pragma unroll
            for (int i = 0; i < 4; i++) {
                int r = row0 + wm * 64 + fm * 16 + lg * 4 + i;
                if (r < N) {
                    int c = bn * 64 + wn * 32 + fn * 16 + lr;
                    if (MODE == 0) {
                        out[r * 128 + c] = acc[fm][fn][i];
                    } else {
                        if (c < 64) out[(size_t)r * 64 + c] = acc[fm][fn][i] + bmu[c];
                        else out[(size_t)N * 64 + (size_t)r * 64 + (c - 64)] = acc[fm][fn][i] + blv[c - 64];
                    }
                }
            }
}

// ---------------- sparse prop: out = z + P*tin  (one wave per node, lane = 2 feats) ----------------

template <int MODE>  // 0: f32 out ; 1: bf16 out = relu(z + P t + bias)
__global__ __launch_bounds__(256) void k_prop(const float* __restrict__ tin, const float* __restrict__ z,
                                              float* __restrict__ toutf, unsigned short* __restrict__ toutb,
                                              const float* __restrict__ bias,
                                              const int* __restrict__ rowp, const int2* __restrict__ pack,
                                              int N, int E) {
    int wave = threadIdx.x >> 6, lane = threadIdx.x & 63;
    int node = blockIdx.x * 4 + wave;
    if (node >= N) return;
    int beg = rowp[node];
    int end = (node == N - 1) ? E : rowp[node + 1];
    float ax = 0.f, ay = 0.f;
    for (int e = beg; e < end; e++) {
        int2 p = pack[e];
        float w = __int_as_float(p.y);
        float2 xv = *reinterpret_cast<const float2*>(&tin[(size_t)p.x * 128 + lane * 2]);
        ax = fmaf(w, xv.x, ax);
        ay = fmaf(w, xv.y, ay);
    }
    float2 zv = *reinterpret_cast<const float2*>(&z[(size_t)node * 128 + lane * 2]);
    float rx = zv.x + ax, ry = zv.y + ay;
    if (MODE == 0) {
        float2 o;
        o.x = rx; o.y = ry;
        *reinterpret_cast<float2*>(&toutf[(size_t)node * 128 + lane * 2]) = o;
    } else {
        rx += bias[lane * 2]; ry += bias[lane * 2 + 1];
        rx = fmaxf(rx, 0.f);  ry = fmaxf(ry, 0.f);
        toutb[(size_t)node * 128 + lane * 2]     = f2bf(rx);
        toutb[(size_t)node * 128 + lane * 2 + 1] = f2bf(ry);
    }
}

// ---------------- launch ----------------

extern "C" void kernel_launch(void* const* d_in, const int* in_sizes, int n_in,
                              void* d_out, int out_size, void* d_ws, size_t ws_size,
                              hipStream_t stream) {
    const float* x   = (const float*)d_in[0];
    const int*   ei  = (const int*)d_in[1];
    const float* pe  = (const float*)d_in[2];
    const float* ew  = (const float*)d_in[3];
    const float* W0  = (const float*)d_in[4];
    const float* b0  = (const float*)d_in[5];
    const float* W1  = (const float*)d_in[6];
    const float* b1  = (const float*)d_in[7];
    const float* Wmu = (const float*)d_in[8];
    const float* bmu = (const float*)d_in[9];
    const float* Wlv = (const float*)d_in[10];
    const float* blv = (const float*)d_in[11];

    const int N = in_sizes[0] / 128;
    const int E = in_sizes[3];
    const int* src = ei;
    const int* dst = ei + E;

    char* ws = (char*)d_ws;
    size_t off = 0;
    auto alloc = [&](size_t bytes) {
        size_t o = off;
        off += (bytes + 1023) & ~(size_t)1023;
        return o;
    };
    float* deg = (float*)(ws + alloc(4 * (size_t)N));   // becomes dis in-place
    int* cnt   = (int*)(ws + alloc(4 * (size_t)N));
    size_t zero_bytes = off;                            // memset deg+cnt
    int* cur   = (int*)(ws + alloc(4 * (size_t)N));
    int* rowp  = (int*)(ws + alloc(4 * (size_t)N));
    int* bsum  = (int*)(ws + alloc(4 * 128));
    unsigned short* AT0 = (unsigned short*)(ws + alloc(2 * 4 * 128 * 160));
    unsigned short* AT1 = (unsigned short*)(ws + alloc(2 * 4 * 128 * 128));
    unsigned short* ATH = (unsigned short*)(ws + alloc(2 * 128 * 128));
    int2* pack = (int2*)(ws + alloc(8 * (size_t)E));
    unsigned short* hb = (unsigned short*)(ws + alloc(2 * (size_t)N * 160));
    float* t0 = (float*)(ws + alloc(4 * (size_t)N * 128));
    float* t1 = (float*)(ws + alloc(4 * (size_t)N * 128));
    float* z  = (float*)d_out;  // N*128 f32 == out_size, scratch until heads GEMM

    hipMemsetAsync(ws, 0, zero_bytes, stream);

    dim3 b256(256);
    k_deg_count<<<dim3((E + 255) / 256), b256, 0, stream>>>(src, dst, ew, deg, cnt, E);
    k_dis<<<dim3((N + 255) / 256), b256, 0, stream>>>(deg, N);
    int nb = (N + 1023) / 1024;
    k_blocksum<<<dim3(nb), dim3(1024), 0, stream>>>(cnt, bsum, N);
    k_scan_bsum<<<dim3(1), dim3(128), 0, stream>>>(bsum, nb);
    k_scan<<<dim3(nb), dim3(1024), 0, stream>>>(cnt, bsum, rowp, cur, N);
    k_build_csr<<<dim3((E + 255) / 256), b256, 0, stream>>>(src, dst, ew, deg, cur, pack, E);
    k_concat<<<dim3((N * 160 + 255) / 256), b256, 0, stream>>>(x, pe, hb, N);
    k_combine<<<dim3((4 * 128 * 160 + 255) / 256), b256, 0, stream>>>(W0, AT0, 144, 160);
    k_combine<<<dim3((4 * 128 * 128 + 255) / 256), b256, 0, stream>>>(W1, AT1, 128, 128);
    k_headsT<<<dim3((128 * 128 + 255) / 256), b256, 0, stream>>>(Wmu, Wlv, ATH);

    dim3 g0((N + 127) / 128, 2);
    dim3 gp((N + 3) / 4);
    // layer 0 (Horner): h = relu(Z0 + P(Z1 + P(Z2 + P Z3)) + b0)
    k_gemm<160, 0><<<g0, b256, 0, stream>>>(hb, AT0 + 3 * 128 * 160, t0, nullptr, nullptr, N);
    k_gemm<160, 0><<<g0, b256, 0, stream>>>(hb, AT0 + 2 * 128 * 160, z, nullptr, nullptr, N);
    k_prop<0><<<gp, b256, 0, stream>>>(t0, z, t1, nullptr, nullptr, rowp, pack, N, E);
    k_gemm<160, 0><<<g0, b256, 0, stream>>>(hb, AT0 + 1 * 128 * 160, z, nullptr, nullptr, N);
    k_prop<0><<<gp, b256, 0, stream>>>(t1, z, t0, nullptr, nullptr, rowp, pack, N, E);
    k_gemm<160, 0><<<g0, b256, 0, stream>>>(hb, AT0, z, nullptr, nullptr, N);
    k_prop<1><<<gp, b256, 0, stream>>>(t0, z, nullptr, hb, b0, rowp, pack, N, E);
    // layer 1 (hb now pitch 128)
    k_gemm<128, 0><<<g0, b256, 0, stream>>>(hb, AT1 + 3 * 128 * 128, t0, nullptr, nullptr, N);
    k_gemm<128, 0><<<g0, b256, 0, stream>>>(hb, AT1 + 2 * 128 * 128, z, nullptr, nullptr, N);
    k_prop<0><<<gp, b256, 0, stream>>>(t0, z, t1, nullptr, nullptr, rowp, pack, N, E);
    k_gemm<128, 0><<<g0, b256, 0, stream>>>(hb, AT1 + 1 * 128 * 128, z, nullptr, nullptr, N);
    k_prop<0><<<gp, b256, 0, stream>>>(t1, z, t0, nullptr, nullptr, rowp, pack, N, E);
    k_gemm<128, 0><<<g0, b256, 0, stream>>>(hb, AT1, z, nullptr, nullptr, N);
    k_prop<1><<<gp, b256, 0, stream>>>(t0, z, nullptr, hb, b1, rowp, pack, N, E);
    // heads: mu | logvar
    k_gemm<128, 1><<<g0, b256, 0, stream>>>(hb, ATH, (float*)d_out, bmu, blv, N);
}

// Round 2
// 1066.895 us; speedup vs baseline: 1.4367x; 1.4367x over previous
//
#include <hip/hip_runtime.h>
#include <hip/hip_bf16.h>

typedef float f32x4 __attribute__((ext_vector_type(4)));
typedef unsigned short u16x8 __attribute__((ext_vector_type(8)));

static __device__ __forceinline__ void mfma16(f32x4& c, const u16x8& a, const u16x8& b) {
    asm("v_mfma_f32_16x16x32_bf16 %0, %1, %2, %0" : "+v"(c) : "v"(a), "v"(b));
}

static __device__ __forceinline__ unsigned short f2bf(float f) {
    __hip_bfloat16 h = __float2bfloat16(f);
    return *reinterpret_cast<unsigned short*>(&h);
}

// ---------------- graph prep ----------------

__global__ __launch_bounds__(256) void k_deg_count(const int* __restrict__ src, const int* __restrict__ dst,
                                                   const float* __restrict__ ew, float* deg, int* cnt, int E) {
    int e = blockIdx.x * 256 + threadIdx.x;
    if (e >= E) return;
    int s = src[e], d = dst[e];
    float w = (s == d) ? 0.f : ew[e];
    atomicAdd(&deg[s], w);
    atomicAdd(&cnt[d], 1);
}

__global__ __launch_bounds__(256) void k_dis(float* deg, int N) {
    int i = blockIdx.x * 256 + threadIdx.x;
    if (i >= N) return;
    float d = deg[i];
    deg[i] = (d > 0.f) ? rsqrtf(d) : 0.f;
}

__global__ __launch_bounds__(1024) void k_blocksum(const int* __restrict__ cnt, int* bsum, int N) {
    __shared__ int sd[1024];
    int i = blockIdx.x * 1024 + threadIdx.x;
    sd[threadIdx.x] = (i < N) ? cnt[i] : 0;
    __syncthreads();
    for (int s = 512; s > 0; s >>= 1) {
        if (threadIdx.x < s) sd[threadIdx.x] += sd[threadIdx.x + s];
        __syncthreads();
    }
    if (threadIdx.x == 0) bsum[blockIdx.x] = sd[0];
}

__global__ __launch_bounds__(128) void k_scan_bsum(int* bsum, int nb) {
    __shared__ int sd[128];
    int t = threadIdx.x;
    int v = (t < nb) ? bsum[t] : 0;
    sd[t] = v;
    __syncthreads();
    for (int d = 1; d < 128; d <<= 1) {
        int x = (t >= d) ? sd[t - d] : 0;
        __syncthreads();
        sd[t] += x;
        __syncthreads();
    }
    if (t < nb) bsum[t] = sd[t] - v;  // exclusive block offsets
}

__global__ __launch_bounds__(1024) void k_scan(const int* __restrict__ cnt, const int* __restrict__ bsum,
                                               int* rowp, int* cur, int N) {
    __shared__ int sd[1024];
    int i = blockIdx.x * 1024 + threadIdx.x;
    int v = (i < N) ? cnt[i] : 0;
    sd[threadIdx.x] = v;
    __syncthreads();
    for (int d = 1; d < 1024; d <<= 1) {
        int x = (threadIdx.x >= d) ? sd[threadIdx.x - d] : 0;
        __syncthreads();
        sd[threadIdx.x] += x;
        __syncthreads();
    }
    if (i < N) {
        int excl = sd[threadIdx.x] - v + bsum[blockIdx.x];
        rowp[i] = excl;
        cur[i]  = excl;
    }
}

__global__ __launch_bounds__(256) void k_build_csr(const int* __restrict__ src, const int* __restrict__ dst,
                                                   const float* __restrict__ ew, const float* __restrict__ dis,
                                                   int* cur, int2* __restrict__ pack, int E) {
    int e = blockIdx.x * 256 + threadIdx.x;
    if (e >= E) return;
    int s = src[e], d = dst[e];
    float w = (s == d) ? 0.f : ew[e];
    float wh = -dis[s] * w * dis[d];
    int pos = atomicAdd(&cur[d], 1);
    int2 p;
    p.x = s;
    p.y = __float_as_int(wh);
    pack[pos] = p;
}

// ---------------- feature prep ----------------

__global__ __launch_bounds__(256) void k_concat(const float* __restrict__ x, const float* __restrict__ pe,
                                                unsigned short* __restrict__ hb, int N) {
    int i = blockIdx.x * 256 + threadIdx.x;
    if (i >= N * 160) return;
    int n = i / 160, k = i - n * 160;
    float v = (k < 128) ? x[n * 128 + k] : (k < 144 ? pe[n * 16 + (k - 128)] : 0.f);
    hb[i] = f2bf(v);
}

// AT[sel][n][kk] = A_sel[kk][n] (transposed, bf16), A0=W0-W2, A1=W1-3W3, A2=2W2, A3=4W3
__global__ __launch_bounds__(256) void k_combine(const float* __restrict__ W, unsigned short* __restrict__ AT,
                                                 int D, int KPAD) {
    int i = blockIdx.x * 256 + threadIdx.x;
    int tot = 4 * 128 * KPAD;
    if (i >= tot) return;
    int sel = i / (128 * KPAD);
    int rem = i - sel * 128 * KPAD;
    int n = rem / KPAD;
    int kk = rem - n * KPAD;
    float v = 0.f;
    if (kk < D) {
        if (sel == 0)      v = W[(0 * D + kk) * 128 + n] - W[(2 * D + kk) * 128 + n];
        else if (sel == 1) v = W[(1 * D + kk) * 128 + n] - 3.f * W[(3 * D + kk) * 128 + n];
        else if (sel == 2) v = 2.f * W[(2 * D + kk) * 128 + n];
        else               v = 4.f * W[(3 * D + kk) * 128 + n];
    }
    AT[i] = f2bf(v);
}

__global__ __launch_bounds__(256) void k_headsT(const float* __restrict__ Wmu, const float* __restrict__ Wlv,
                                                unsigned short* __restrict__ AT) {
    int i = blockIdx.x * 256 + threadIdx.x;
    if (i >= 128 * 128) return;
    int n = i >> 7, kk = i & 127;
    float v = (n < 64) ? Wmu[kk * 64 + n] : Wlv[kk * 64 + (n - 64)];
    AT[i] = f2bf(v);
}

// ---------------- pair GEMM: Ca = hb@Wa^T, Cb = hb@Wb^T (bf16 out), BM=64 ----------------
// Bta/Btb are [128][KPAD] transposed weights. grid = ((N+63)/64, 2); bn picks 64-col half.

template <int KPAD>
__global__ __launch_bounds__(256) void k_gemm_pair(const unsigned short* __restrict__ Abf,
                                                   const unsigned short* __restrict__ Bta,
                                                   const unsigned short* __restrict__ Btb,
                                                   unsigned short* __restrict__ outA,
                                                   unsigned short* __restrict__ outB,
                                                   int N) {
    constexpr int LP = KPAD + 8;
    __shared__ __align__(16) unsigned short As[64 * LP];
    __shared__ __align__(16) unsigned short Bs[128 * LP];
    const int tid = threadIdx.x;
    const int row0 = blockIdx.x * 64;
    const int bn = blockIdx.y;

    {   // stage A tile (64 x KPAD)
        constexpr int TOT = 64 * KPAD;
        for (int c = tid * 8; c < TOT; c += 256 * 8) {
            int r = c / KPAD;
            int k = c - r * KPAD;
            int gr = row0 + r;
            if (gr > N - 1) gr = N - 1;
            u16x8 v = *reinterpret_cast<const u16x8*>(&Abf[(size_t)gr * KPAD + k]);
            *reinterpret_cast<u16x8*>(&As[r * LP + k]) = v;
        }
    }
    {   // stage B tiles: rows 0..63 = Wa cols [bn*64..), rows 64..127 = Wb cols [bn*64..)
        constexpr int TOT = 128 * KPAD;
        for (int c = tid * 8; c < TOT; c += 256 * 8) {
            int r = c / KPAD;
            int k = c - r * KPAD;
            const unsigned short* srcp = (r < 64) ? &Bta[(size_t)(bn * 64 + r) * KPAD + k]
                                                  : &Btb[(size_t)(bn * 64 + r - 64) * KPAD + k];
            u16x8 v = *reinterpret_cast<const u16x8*>(srcp);
            *reinterpret_cast<u16x8*>(&Bs[r * LP + k]) = v;
        }
    }
    __syncthreads();

    const int wave = tid >> 6, lane = tid & 63;
    const int wm = wave >> 1, wn = wave & 1;  // wm: row half (32), wn: weight select
    const int lr = lane & 15, lg = lane >> 4;

    f32x4 acc[2][4];
#pragma unroll
    for (int i = 0; i < 2; i++)
#pragma unroll
        for (int j = 0; j < 4; j++) acc[i][j] = (f32x4){0.f, 0.f, 0.f, 0.f};

    asm volatile("s_nop 7"
                 : "+v"(acc[0][0]), "+v"(acc[0][1]), "+v"(acc[0][2]), "+v"(acc[0][3]),
                   "+v"(acc[1][0]), "+v"(acc[1][1]), "+v"(acc[1][2]), "+v"(acc[1][3]));

    constexpr int KS = KPAD / 32;
#pragma unroll
    for (int ks = 0; ks < KS; ks++) {
        u16x8 a[2], b[4];
#pragma unroll
        for (int fm = 0; fm < 2; fm++)
            a[fm] = *reinterpret_cast<const u16x8*>(&As[(wm * 32 + fm * 16 + lr) * LP + ks * 32 + lg * 8]);
#pragma unroll
        for (int fn = 0; fn < 4; fn++)
            b[fn] = *reinterpret_cast<const u16x8*>(&Bs[(wn * 64 + fn * 16 + lr) * LP + ks * 32 + lg * 8]);
#pragma unroll
        for (int fm = 0; fm < 2; fm++)
#pragma unroll
            for (int fn = 0; fn < 4; fn++) mfma16(acc[fm][fn], a[fm], b[fn]);
    }

    asm volatile("s_nop 7\n\ts_nop 7\n\ts_nop 7"
                 : "+v"(acc[0][0]), "+v"(acc[0][1]), "+v"(acc[0][2]), "+v"(acc[0][3]),
                   "+v"(acc[1][0]), "+v"(acc[1][1]), "+v"(acc[1][2]), "+v"(acc[1][3]));

    unsigned short* outp = (wn == 0) ? outA : outB;
#pragma unroll
    for (int fm = 0; fm < 2; fm++)
#pragma unroll
        for (int fn = 0; fn < 4; fn++)
#pragma unroll
            for (int i = 0; i < 4; i++) {
                int r = row0 + wm * 32 + fm * 16 + lg * 4 + i;
                if (r < N) {
                    int c = bn * 64 + fn * 16 + lr;
                    outp[(size_t)r * 128 + c] = f2bf(acc[fm][fn][i]);
                }
            }
}

// ---------------- heads GEMM: [mu|logvar](f32) = h(bf16) @ ATH^T + bias ----------------

__global__ __launch_bounds__(256) void k_gemm_heads(const unsigned short* __restrict__ Abf,
                                                    const unsigned short* __restrict__ Bt,
                                                    float* __restrict__ out,
                                                    const float* __restrict__ bmu, const float* __restrict__ blv,
                                                    int N) {
    constexpr int KPAD = 128;
    constexpr int LP = KPAD + 8;
    __shared__ __align__(16) unsigned short As[128 * LP];
    __shared__ __align__(16) unsigned short Bs[64 * LP];
    const int tid = threadIdx.x;
    const int row0 = blockIdx.x * 128;
    const int bn = blockIdx.y;

    {
        constexpr int TOT = 128 * KPAD;
        for (int c = tid * 8; c < TOT; c += 256 * 8) {
            int r = c / KPAD;
            int k = c - r * KPAD;
            int gr = row0 + r;
            if (gr > N - 1) gr = N - 1;
            u16x8 v = *reinterpret_cast<const u16x8*>(&Abf[(size_t)gr * KPAD + k]);
            *reinterpret_cast<u16x8*>(&As[r * LP + k]) = v;
        }
    }
    {
        constexpr int TOT = 64 * KPAD;
        for (int c = tid * 8; c < TOT; c += 256 * 8) {
            int r = c / KPAD;
            int k = c - r * KPAD;
            u16x8 v = *reinterpret_cast<const u16x8*>(&Bt[(size_t)(bn * 64 + r) * KPAD + k]);
            *reinterpret_cast<u16x8*>(&Bs[r * LP + k]) = v;
        }
    }
    __syncthreads();

    const int wave = tid >> 6, lane = tid & 63;
    const int wm = wave >> 1, wn = wave & 1;
    const int lr = lane & 15, lg = lane >> 4;

    f32x4 acc[4][2];
#pragma unroll
    for (int i = 0; i < 4; i++)
#pragma unroll
        for (int j = 0; j < 2; j++) acc[i][j] = (f32x4){0.f, 0.f, 0.f, 0.f};

    asm volatile("s_nop 7"
                 : "+v"(acc[0][0]), "+v"(acc[0][1]), "+v"(acc[1][0]), "+v"(acc[1][1]),
                   "+v"(acc[2][0]), "+v"(acc[2][1]), "+v"(acc[3][0]), "+v"(acc[3][1]));

#pragma unroll
    for (int ks = 0; ks < KPAD / 32; ks++) {
        u16x8 a[4], b[2];
#pragma unroll
        for (int fm = 0; fm < 4; fm++)
            a[fm] = *reinterpret_cast<const u16x8*>(&As[(wm * 64 + fm * 16 + lr) * LP + ks * 32 + lg * 8]);
#pragma unroll
        for (int fn = 0; fn < 2; fn++)
            b[fn] = *reinterpret_cast<const u16x8*>(&Bs[(wn * 32 + fn * 16 + lr) * LP + ks * 32 + lg * 8]);
#pragma unroll
        for (int fm = 0; fm < 4; fm++)
#pragma unroll
            for (int fn = 0; fn < 2; fn++) mfma16(acc[fm][fn], a[fm], b[fn]);
    }

    asm volatile("s_nop 7\n\ts_nop 7\n\ts_nop 7"
                 : "+v"(acc[0][0]), "+v"(acc[0][1]), "+v"(acc[1][0]), "+v"(acc[1][1]),
                   "+v"(acc[2][0]), "+v"(acc[2][1]), "+v"(acc[3][0]), "+v"(acc[3][1]));

#pragma unroll
    for (int fm = 0; fm < 4; fm++)
#pragma unroll
        for (int fn = 0; fn < 2; fn++)
#pragma unroll
            for (int i = 0; i < 4; i++) {
                int r = row0 + wm * 64 + fm * 16 + lg * 4 + i;
                if (r < N) {
                    int c = bn * 64 + wn * 32 + fn * 16 + lr;
                    if (c < 64) out[(size_t)r * 64 + c] = acc[fm][fn][i] + bmu[c];
                    else out[(size_t)N * 64 + (size_t)r * 64 + (c - 64)] = acc[fm][fn][i] + blv[c - 64];
                }
            }
}

// ---------------- sparse prop: tout = [relu](z + P*tin [+ bias])  — all bf16, fp32 accum ----------------

template <int MODE>  // 0: plain ; 1: + bias, relu
__global__ __launch_bounds__(256) void k_prop(const unsigned int* __restrict__ tin,
                                              const unsigned int* __restrict__ z,
                                              unsigned int* __restrict__ tout,
                                              const float* __restrict__ bias,
                                              const int* __restrict__ rowp, const int2* __restrict__ pack,
                                              int N, int E) {
    int wave = threadIdx.x >> 6, lane = threadIdx.x & 63;
    int node = blockIdx.x * 4 + wave;
    if (node >= N) return;
    int beg = rowp[node];
    int end = (node == N - 1) ? E : rowp[node + 1];
    float ax = 0.f, ay = 0.f;
    int e = beg;
    for (; e + 1 < end; e += 2) {
        int2 p0 = pack[e];
        int2 p1 = pack[e + 1];
        unsigned int v0 = tin[(size_t)p0.x * 64 + lane];
        unsigned int v1 = tin[(size_t)p1.x * 64 + lane];
        float w0 = __int_as_float(p0.y), w1 = __int_as_float(p1.y);
        ax = fmaf(w0, __uint_as_float(v0 << 16), ax);
        ay = fmaf(w0, __uint_as_float(v0 & 0xffff0000u), ay);
        ax = fmaf(w1, __uint_as_float(v1 << 16), ax);
        ay = fmaf(w1, __uint_as_float(v1 & 0xffff0000u), ay);
    }
    if (e < end) {
        int2 p0 = pack[e];
        unsigned int v0 = tin[(size_t)p0.x * 64 + lane];
        float w0 = __int_as_float(p0.y);
        ax = fmaf(w0, __uint_as_float(v0 << 16), ax);
        ay = fmaf(w0, __uint_as_float(v0 & 0xffff0000u), ay);
    }
    unsigned int zv = z[(size_t)node * 64 + lane];
    float rx = __uint_as_float(zv << 16) + ax;
    float ry = __uint_as_float(zv & 0xffff0000u) + ay;
    if (MODE == 1) {
        rx = fmaxf(rx + bias[lane * 2], 0.f);
        ry = fmaxf(ry + bias[lane * 2 + 1], 0.f);
    }
    unsigned int lo = f2bf(rx), hi = f2bf(ry);
    tout[(size_t)node * 64 + lane] = lo | (hi << 16);
}

// ---------------- launch ----------------

extern "C" void kernel_launch(void* const* d_in, const int* in_sizes, int n_in,
                              void* d_out, int out_size, void* d_ws, size_t ws_size,
                              hipStream_t stream) {
    const float* x   = (const float*)d_in[0];
    const int*   ei  = (const int*)d_in[1];
    const float* pe  = (const float*)d_in[2];
    const float* ew  = (const float*)d_in[3];
    const float* W0  = (const float*)d_in[4];
    const float* b0  = (const float*)d_in[5];
    const float* W1  = (const float*)d_in[6];
    const float* b1  = (const float*)d_in[7];
    const float* Wmu = (const float*)d_in[8];
    const float* bmu = (const float*)d_in[9];
    const float* Wlv = (const float*)d_in[10];
    const float* blv = (const float*)d_in[11];

    const int N = in_sizes[0] / 128;
    const int E = in_sizes[3];
    const int* src = ei;
    const int* dst = ei + E;

    char* ws = (char*)d_ws;
    size_t off = 0;
    auto alloc = [&](size_t bytes) {
        size_t o = off;
        off += (bytes + 1023) & ~(size_t)1023;
        return o;
    };
    float* deg = (float*)(ws + alloc(4 * (size_t)N));   // becomes dis in-place
    int* cnt   = (int*)(ws + alloc(4 * (size_t)N));
    size_t zero_bytes = off;                            // memset deg+cnt
    int* cur   = (int*)(ws + alloc(4 * (size_t)N));
    int* rowp  = (int*)(ws + alloc(4 * (size_t)N));
    int* bsum  = (int*)(ws + alloc(4 * 128));
    unsigned short* AT0 = (unsigned short*)(ws + alloc(2 * 4 * 128 * 160));
    unsigned short* AT1 = (unsigned short*)(ws + alloc(2 * 4 * 128 * 128));
    unsigned short* ATH = (unsigned short*)(ws + alloc(2 * 128 * 128));
    int2* pack = (int2*)(ws + alloc(8 * (size_t)E));
    unsigned short* hb = (unsigned short*)(ws + alloc(2 * (size_t)N * 160));
    unsigned int* za = (unsigned int*)(ws + alloc(2 * (size_t)N * 128));
    unsigned int* zb = (unsigned int*)(ws + alloc(2 * (size_t)N * 128));
    unsigned int* t1 = (unsigned int*)(ws + alloc(2 * (size_t)N * 128));
    unsigned int* t2 = (unsigned int*)(ws + alloc(2 * (size_t)N * 128));

    hipMemsetAsync(ws, 0, zero_bytes, stream);

    dim3 b256(256);
    k_deg_count<<<dim3((E + 255) / 256), b256, 0, stream>>>(src, dst, ew, deg, cnt, E);
    k_dis<<<dim3((N + 255) / 256), b256, 0, stream>>>(deg, N);
    int nb = (N + 1023) / 1024;
    k_blocksum<<<dim3(nb), dim3(1024), 0, stream>>>(cnt, bsum, N);
    k_scan_bsum<<<dim3(1), dim3(128), 0, stream>>>(bsum, nb);
    k_scan<<<dim3(nb), dim3(1024), 0, stream>>>(cnt, bsum, rowp, cur, N);
    k_build_csr<<<dim3((E + 255) / 256), b256, 0, stream>>>(src, dst, ew, deg, cur, pack, E);
    k_concat<<<dim3((N * 160 + 255) / 256), b256, 0, stream>>>(x, pe, hb, N);
    k_combine<<<dim3((4 * 128 * 160 + 255) / 256), b256, 0, stream>>>(W0, AT0, 144, 160);
    k_combine<<<dim3((4 * 128 * 128 + 255) / 256), b256, 0, stream>>>(W1, AT1, 128, 128);
    k_headsT<<<dim3((128 * 128 + 255) / 256), b256, 0, stream>>>(Wmu, Wlv, ATH);

    dim3 gg((N + 63) / 64, 2);
    dim3 gh((N + 127) / 128, 2);
    dim3 gp((N + 3) / 4);
    const unsigned short* hbu = hb;

    // layer 0 (Horner): h1 = relu(Z0 + P(Z1 + P(Z2 + P Z3)) + b0)
    k_gemm_pair<160><<<gg, b256, 0, stream>>>(hbu, AT0 + 3 * 128 * 160, AT0 + 2 * 128 * 160,
                                              (unsigned short*)za, (unsigned short*)zb, N);   // za=Z3 zb=Z2
    k_prop<0><<<gp, b256, 0, stream>>>(za, zb, t1, nullptr, rowp, pack, N, E);                // t1 = Z2 + P Z3
    k_gemm_pair<160><<<gg, b256, 0, stream>>>(hbu, AT0 + 1 * 128 * 160, AT0 + 0 * 128 * 160,
                                              (unsigned short*)za, (unsigned short*)zb, N);   // za=Z1 zb=Z0
    k_prop<0><<<gp, b256, 0, stream>>>(t1, za, t2, nullptr, rowp, pack, N, E);                // t2 = Z1 + P t1
    k_prop<1><<<gp, b256, 0, stream>>>(t2, zb, t1, b0, rowp, pack, N, E);                     // h1 = relu(Z0 + P t2 + b0) -> t1

    // layer 1 (input t1, pitch 128)
    const unsigned short* h1 = (const unsigned short*)t1;
    k_gemm_pair<128><<<gg, b256, 0, stream>>>(h1, AT1 + 3 * 128 * 128, AT1 + 2 * 128 * 128,
                                              (unsigned short*)za, (unsigned short*)zb, N);
    k_prop<0><<<gp, b256, 0, stream>>>(za, zb, t2, nullptr, rowp, pack, N, E);
    k_gemm_pair<128><<<gg, b256, 0, stream>>>(h1, AT1 + 1 * 128 * 128, AT1 + 0 * 128 * 128,
                                              (unsigned short*)za, (unsigned short*)zb, N);
    k_prop<0><<<gp, b256, 0, stream>>>(t2, za, t1, nullptr, rowp, pack, N, E);                // t1 free after gemms
    k_prop<1><<<gp, b256, 0, stream>>>(t1, zb, t2, b1, rowp, pack, N, E);                     // h2 -> t2

    // heads
    k_gemm_heads<<<gh, b256, 0, stream>>>((const unsigned short*)t2, ATH, (float*)d_out, bmu, blv, N);
}

// Round 3
// 977.759 us; speedup vs baseline: 1.5676x; 1.0912x over previous
//
#include <hip/hip_runtime.h>
#include <hip/hip_bf16.h>

typedef float f32x4 __attribute__((ext_vector_type(4)));
typedef unsigned short u16x8 __attribute__((ext_vector_type(8)));

static __device__ __forceinline__ void mfma16(f32x4& c, const u16x8& a, const u16x8& b) {
    asm("v_mfma_f32_16x16x32_bf16 %0, %1, %2, %0" : "+v"(c) : "v"(a), "v"(b));
}

static __device__ __forceinline__ unsigned short f2bf(float f) {
    __hip_bfloat16 h = __float2bfloat16(f);
    return *reinterpret_cast<unsigned short*>(&h);
}

// ---------------- graph prep ----------------

// deg[s] += w (float atomic); rank[e] = arrival index within dst bucket (returned by cnt atomic)
__global__ __launch_bounds__(256) void k_deg_rank(const int* __restrict__ src, const int* __restrict__ dst,
                                                  const float* __restrict__ ew, float* deg, int* cnt,
                                                  int* __restrict__ rank, int E) {
    int base = blockIdx.x * 1024 + threadIdx.x;
#pragma unroll
    for (int u = 0; u < 4; u++) {
        int e = base + u * 256;
        if (e < E) {
            int s = src[e], d = dst[e];
            float w = (s == d) ? 0.f : ew[e];
            atomicAdd(&deg[s], w);
            rank[e] = atomicAdd(&cnt[d], 1);
        }
    }
}

__global__ __launch_bounds__(256) void k_dis(float* deg, int N) {
    int i = blockIdx.x * 256 + threadIdx.x;
    if (i >= N) return;
    float d = deg[i];
    deg[i] = (d > 0.f) ? rsqrtf(d) : 0.f;
}

__global__ __launch_bounds__(1024) void k_blocksum(const int* __restrict__ cnt, int* bsum, int N) {
    __shared__ int sd[1024];
    int i = blockIdx.x * 1024 + threadIdx.x;
    sd[threadIdx.x] = (i < N) ? cnt[i] : 0;
    __syncthreads();
    for (int s = 512; s > 0; s >>= 1) {
        if (threadIdx.x < s) sd[threadIdx.x] += sd[threadIdx.x + s];
        __syncthreads();
    }
    if (threadIdx.x == 0) bsum[blockIdx.x] = sd[0];
}

__global__ __launch_bounds__(128) void k_scan_bsum(int* bsum, int nb) {
    __shared__ int sd[128];
    int t = threadIdx.x;
    int v = (t < nb) ? bsum[t] : 0;
    sd[t] = v;
    __syncthreads();
    for (int d = 1; d < 128; d <<= 1) {
        int x = (t >= d) ? sd[t - d] : 0;
        __syncthreads();
        sd[t] += x;
        __syncthreads();
    }
    if (t < nb) bsum[t] = sd[t] - v;  // exclusive block offsets
}

__global__ __launch_bounds__(1024) void k_scan(const int* __restrict__ cnt, const int* __restrict__ bsum,
                                               int* rowp, int N) {
    __shared__ int sd[1024];
    int i = blockIdx.x * 1024 + threadIdx.x;
    int v = (i < N) ? cnt[i] : 0;
    sd[threadIdx.x] = v;
    __syncthreads();
    for (int d = 1; d < 1024; d <<= 1) {
        int x = (threadIdx.x >= d) ? sd[threadIdx.x - d] : 0;
        __syncthreads();
        sd[threadIdx.x] += x;
        __syncthreads();
    }
    if (i < N) rowp[i] = sd[threadIdx.x] - v + bsum[blockIdx.x];
}

// atomic-free CSR fill: pos = rowp[dst] + rank
__global__ __launch_bounds__(256) void k_build_csr(const int* __restrict__ src, const int* __restrict__ dst,
                                                   const float* __restrict__ ew, const float* __restrict__ dis,
                                                   const int* __restrict__ rowp, const int* __restrict__ rank,
                                                   int2* __restrict__ pack, int E) {
    int base = blockIdx.x * 512 + threadIdx.x;
#pragma unroll
    for (int u = 0; u < 2; u++) {
        int e = base + u * 256;
        if (e < E) {
            int s = src[e], d = dst[e];
            float w = (s == d) ? 0.f : ew[e];
            float wh = -dis[s] * w * dis[d];
            int pos = rowp[d] + rank[e];
            int2 p;
            p.x = s;
            p.y = __float_as_int(wh);
            pack[pos] = p;
        }
    }
}

// ---------------- feature prep ----------------

__global__ __launch_bounds__(256) void k_concat(const float* __restrict__ x, const float* __restrict__ pe,
                                                unsigned short* __restrict__ hb, int N) {
    int i = blockIdx.x * 256 + threadIdx.x;
    if (i >= N * 160) return;
    int n = i / 160, k = i - n * 160;
    float v = (k < 128) ? x[n * 128 + k] : (k < 144 ? pe[n * 16 + (k - 128)] : 0.f);
    hb[i] = f2bf(v);
}

// AT[sel][n][kk] = A_sel[kk][n] (transposed, bf16), A0=W0-W2, A1=W1-3W3, A2=2W2, A3=4W3
__global__ __launch_bounds__(256) void k_combine(const float* __restrict__ W, unsigned short* __restrict__ AT,
                                                 int D, int KPAD) {
    int i = blockIdx.x * 256 + threadIdx.x;
    int tot = 4 * 128 * KPAD;
    if (i >= tot) return;
    int sel = i / (128 * KPAD);
    int rem = i - sel * 128 * KPAD;
    int n = rem / KPAD;
    int kk = rem - n * KPAD;
    float v = 0.f;
    if (kk < D) {
        if (sel == 0)      v = W[(0 * D + kk) * 128 + n] - W[(2 * D + kk) * 128 + n];
        else if (sel == 1) v = W[(1 * D + kk) * 128 + n] - 3.f * W[(3 * D + kk) * 128 + n];
        else if (sel == 2) v = 2.f * W[(2 * D + kk) * 128 + n];
        else               v = 4.f * W[(3 * D + kk) * 128 + n];
    }
    AT[i] = f2bf(v);
}

__global__ __launch_bounds__(256) void k_headsT(const float* __restrict__ Wmu, const float* __restrict__ Wlv,
                                                unsigned short* __restrict__ AT) {
    int i = blockIdx.x * 256 + threadIdx.x;
    if (i >= 128 * 128) return;
    int n = i >> 7, kk = i & 127;
    float v = (n < 64) ? Wmu[kk * 64 + n] : Wlv[kk * 64 + (n - 64)];
    AT[i] = f2bf(v);
}

// ---------------- pair GEMM: Ca = hb@Wa^T, Cb = hb@Wb^T (bf16 out), BM=64 ----------------

template <int KPAD>
__global__ __launch_bounds__(256) void k_gemm_pair(const unsigned short* __restrict__ Abf,
                                                   const unsigned short* __restrict__ Bta,
                                                   const unsigned short* __restrict__ Btb,
                                                   unsigned short* __restrict__ outA,
                                                   unsigned short* __restrict__ outB,
                                                   int N) {
    constexpr int LP = KPAD + 8;
    __shared__ __align__(16) unsigned short As[64 * LP];
    __shared__ __align__(16) unsigned short Bs[128 * LP];
    const int tid = threadIdx.x;
    const int row0 = blockIdx.x * 64;
    const int bn = blockIdx.y;

    {
        constexpr int TOT = 64 * KPAD;
        for (int c = tid * 8; c < TOT; c += 256 * 8) {
            int r = c / KPAD;
            int k = c - r * KPAD;
            int gr = row0 + r;
            if (gr > N - 1) gr = N - 1;
            u16x8 v = *reinterpret_cast<const u16x8*>(&Abf[(size_t)gr * KPAD + k]);
            *reinterpret_cast<u16x8*>(&As[r * LP + k]) = v;
        }
    }
    {
        constexpr int TOT = 128 * KPAD;
        for (int c = tid * 8; c < TOT; c += 256 * 8) {
            int r = c / KPAD;
            int k = c - r * KPAD;
            const unsigned short* srcp = (r < 64) ? &Bta[(size_t)(bn * 64 + r) * KPAD + k]
                                                  : &Btb[(size_t)(bn * 64 + r - 64) * KPAD + k];
            u16x8 v = *reinterpret_cast<const u16x8*>(srcp);
            *reinterpret_cast<u16x8*>(&Bs[r * LP + k]) = v;
        }
    }
    __syncthreads();

    const int wave = tid >> 6, lane = tid & 63;
    const int wm = wave >> 1, wn = wave & 1;
    const int lr = lane & 15, lg = lane >> 4;

    f32x4 acc[2][4];
#pragma unroll
    for (int i = 0; i < 2; i++)
#pragma unroll
        for (int j = 0; j < 4; j++) acc[i][j] = (f32x4){0.f, 0.f, 0.f, 0.f};

    asm volatile("s_nop 7"
                 : "+v"(acc[0][0]), "+v"(acc[0][1]), "+v"(acc[0][2]), "+v"(acc[0][3]),
                   "+v"(acc[1][0]), "+v"(acc[1][1]), "+v"(acc[1][2]), "+v"(acc[1][3]));

    constexpr int KS = KPAD / 32;
#pragma unroll
    for (int ks = 0; ks < KS; ks++) {
        u16x8 a[2], b[4];
#pragma unroll
        for (int fm = 0; fm < 2; fm++)
            a[fm] = *reinterpret_cast<const u16x8*>(&As[(wm * 32 + fm * 16 + lr) * LP + ks * 32 + lg * 8]);
#pragma unroll
        for (int fn = 0; fn < 4; fn++)
            b[fn] = *reinterpret_cast<const u16x8*>(&Bs[(wn * 64 + fn * 16 + lr) * LP + ks * 32 + lg * 8]);
#pragma unroll
        for (int fm = 0; fm < 2; fm++)
#pragma unroll
            for (int fn = 0; fn < 4; fn++) mfma16(acc[fm][fn], a[fm], b[fn]);
    }

    asm volatile("s_nop 7\n\ts_nop 7\n\ts_nop 7"
                 : "+v"(acc[0][0]), "+v"(acc[0][1]), "+v"(acc[0][2]), "+v"(acc[0][3]),
                   "+v"(acc[1][0]), "+v"(acc[1][1]), "+v"(acc[1][2]), "+v"(acc[1][3]));

    unsigned short* outp = (wn == 0) ? outA : outB;
#pragma unroll
    for (int fm = 0; fm < 2; fm++)
#pragma unroll
        for (int fn = 0; fn < 4; fn++)
#pragma unroll
            for (int i = 0; i < 4; i++) {
                int r = row0 + wm * 32 + fm * 16 + lg * 4 + i;
                if (r < N) {
                    int c = bn * 64 + fn * 16 + lr;
                    outp[(size_t)r * 128 + c] = f2bf(acc[fm][fn][i]);
                }
            }
}

// ---------------- heads GEMM: [mu|logvar](f32) = h(bf16) @ ATH^T + bias ----------------

__global__ __launch_bounds__(256) void k_gemm_heads(const unsigned short* __restrict__ Abf,
                                                    const unsigned short* __restrict__ Bt,
                                                    float* __restrict__ out,
                                                    const float* __restrict__ bmu, const float* __restrict__ blv,
                                                    int N) {
    constexpr int KPAD = 128;
    constexpr int LP = KPAD + 8;
    __shared__ __align__(16) unsigned short As[128 * LP];
    __shared__ __align__(16) unsigned short Bs[64 * LP];
    const int tid = threadIdx.x;
    const int row0 = blockIdx.x * 128;
    const int bn = blockIdx.y;

    {
        constexpr int TOT = 128 * KPAD;
        for (int c = tid * 8; c < TOT; c += 256 * 8) {
            int r = c / KPAD;
            int k = c - r * KPAD;
            int gr = row0 + r;
            if (gr > N - 1) gr = N - 1;
            u16x8 v = *reinterpret_cast<const u16x8*>(&Abf[(size_t)gr * KPAD + k]);
            *reinterpret_cast<u16x8*>(&As[r * LP + k]) = v;
        }
    }
    {
        constexpr int TOT = 64 * KPAD;
        for (int c = tid * 8; c < TOT; c += 256 * 8) {
            int r = c / KPAD;
            int k = c - r * KPAD;
            u16x8 v = *reinterpret_cast<const u16x8*>(&Bt[(size_t)(bn * 64 + r) * KPAD + k]);
            *reinterpret_cast<u16x8*>(&Bs[r * LP + k]) = v;
        }
    }
    __syncthreads();

    const int wave = tid >> 6, lane = tid & 63;
    const int wm = wave >> 1, wn = wave & 1;
    const int lr = lane & 15, lg = lane >> 4;

    f32x4 acc[4][2];
#pragma unroll
    for (int i = 0; i < 4; i++)
#pragma unroll
        for (int j = 0; j < 2; j++) acc[i][j] = (f32x4){0.f, 0.f, 0.f, 0.f};

    asm volatile("s_nop 7"
                 : "+v"(acc[0][0]), "+v"(acc[0][1]), "+v"(acc[1][0]), "+v"(acc[1][1]),
                   "+v"(acc[2][0]), "+v"(acc[2][1]), "+v"(acc[3][0]), "+v"(acc[3][1]));

#pragma unroll
    for (int ks = 0; ks < KPAD / 32; ks++) {
        u16x8 a[4], b[2];
#pragma unroll
        for (int fm = 0; fm < 4; fm++)
            a[fm] = *reinterpret_cast<const u16x8*>(&As[(wm * 64 + fm * 16 + lr) * LP + ks * 32 + lg * 8]);
#pragma unroll
        for (int fn = 0; fn < 2; fn++)
            b[fn] = *reinterpret_cast<const u16x8*>(&Bs[(wn * 32 + fn * 16 + lr) * LP + ks * 32 + lg * 8]);
#pragma unroll
        for (int fm = 0; fm < 4; fm++)
#pragma unroll
            for (int fn = 0; fn < 2; fn++) mfma16(acc[fm][fn], a[fm], b[fn]);
    }

    asm volatile("s_nop 7\n\ts_nop 7\n\ts_nop 7"
                 : "+v"(acc[0][0]), "+v"(acc[0][1]), "+v"(acc[1][0]), "+v"(acc[1][1]),
                   "+v"(acc[2][0]), "+v"(acc[2][1]), "+v"(acc[3][0]), "+v"(acc[3][1]));

#pragma unroll
    for (int fm = 0; fm < 4; fm++)
#pragma unroll
        for (int fn = 0; fn < 2; fn++)
#pragma unroll
            for (int i = 0; i < 4; i++) {
                int r = row0 + wm * 64 + fm * 16 + lg * 4 + i;
                if (r < N) {
                    int c = bn * 64 + wn * 32 + fn * 16 + lr;
                    if (c < 64) out[(size_t)r * 64 + c] = acc[fm][fn][i] + bmu[c];
                    else out[(size_t)N * 64 + (size_t)r * 64 + (c - 64)] = acc[fm][fn][i] + blv[c - 64];
                }
            }
}

// ---------------- sparse prop: tout = [relu](z + P*tin [+ bias])  — all bf16, fp32 accum ----------------

template <int MODE>  // 0: plain ; 1: + bias, relu
__global__ __launch_bounds__(256) void k_prop(const unsigned int* __restrict__ tin,
                                              const unsigned int* __restrict__ z,
                                              unsigned int* __restrict__ tout,
                                              const float* __restrict__ bias,
                                              const int* __restrict__ rowp,
                                              const long long* __restrict__ pack,
                                              int N, int E) {
    int wave = threadIdx.x >> 6, lane = threadIdx.x & 63;
    int node = blockIdx.x * 4 + wave;
    if (node >= N) return;
    int beg = rowp[node];
    int end = (node == N - 1) ? E : rowp[node + 1];
    float ax = 0.f, ay = 0.f;
    int e = beg;
    for (; e + 3 < end; e += 4) {
        long long q0 = __builtin_nontemporal_load(pack + e);
        long long q1 = __builtin_nontemporal_load(pack + e + 1);
        long long q2 = __builtin_nontemporal_load(pack + e + 2);
        long long q3 = __builtin_nontemporal_load(pack + e + 3);
        unsigned int v0 = tin[(size_t)(unsigned int)q0 * 64 + lane];
        unsigned int v1 = tin[(size_t)(unsigned int)q1 * 64 + lane];
        unsigned int v2 = tin[(size_t)(unsigned int)q2 * 64 + lane];
        unsigned int v3 = tin[(size_t)(unsigned int)q3 * 64 + lane];
        float w0 = __uint_as_float((unsigned int)((unsigned long long)q0 >> 32));
        float w1 = __uint_as_float((unsigned int)((unsigned long long)q1 >> 32));
        float w2 = __uint_as_float((unsigned int)((unsigned long long)q2 >> 32));
        float w3 = __uint_as_float((unsigned int)((unsigned long long)q3 >> 32));
        ax = fmaf(w0, __uint_as_float(v0 << 16), ax);
        ay = fmaf(w0, __uint_as_float(v0 & 0xffff0000u), ay);
        ax = fmaf(w1, __uint_as_float(v1 << 16), ax);
        ay = fmaf(w1, __uint_as_float(v1 & 0xffff0000u), ay);
        ax = fmaf(w2, __uint_as_float(v2 << 16), ax);
        ay = fmaf(w2, __uint_as_float(v2 & 0xffff0000u), ay);
        ax = fmaf(w3, __uint_as_float(v3 << 16), ax);
        ay = fmaf(w3, __uint_as_float(v3 & 0xffff0000u), ay);
    }
    for (; e < end; e++) {
        long long q0 = __builtin_nontemporal_load(pack + e);
        unsigned int v0 = tin[(size_t)(unsigned int)q0 * 64 + lane];
        float w0 = __uint_as_float((unsigned int)((unsigned long long)q0 >> 32));
        ax = fmaf(w0, __uint_as_float(v0 << 16), ax);
        ay = fmaf(w0, __uint_as_float(v0 & 0xffff0000u), ay);
    }
    unsigned int zv = __builtin_nontemporal_load(z + (size_t)node * 64 + lane);
    float rx = __uint_as_float(zv << 16) + ax;
    float ry = __uint_as_float(zv & 0xffff0000u) + ay;
    if (MODE == 1) {
        rx = fmaxf(rx + bias[lane * 2], 0.f);
        ry = fmaxf(ry + bias[lane * 2 + 1], 0.f);
    }
    unsigned int lo = f2bf(rx), hi = f2bf(ry);
    tout[(size_t)node * 64 + lane] = lo | (hi << 16);
}

// ---------------- launch ----------------

extern "C" void kernel_launch(void* const* d_in, const int* in_sizes, int n_in,
                              void* d_out, int out_size, void* d_ws, size_t ws_size,
                              hipStream_t stream) {
    const float* x   = (const float*)d_in[0];
    const int*   ei  = (const int*)d_in[1];
    const float* pe  = (const float*)d_in[2];
    const float* ew  = (const float*)d_in[3];
    const float* W0  = (const float*)d_in[4];
    const float* b0  = (const float*)d_in[5];
    const float* W1  = (const float*)d_in[6];
    const float* b1  = (const float*)d_in[7];
    const float* Wmu = (const float*)d_in[8];
    const float* bmu = (const float*)d_in[9];
    const float* Wlv = (const float*)d_in[10];
    const float* blv = (const float*)d_in[11];

    const int N = in_sizes[0] / 128;
    const int E = in_sizes[3];
    const int* src = ei;
    const int* dst = ei + E;

    char* ws = (char*)d_ws;
    size_t off = 0;
    auto alloc = [&](size_t bytes) {
        size_t o = off;
        off += (bytes + 1023) & ~(size_t)1023;
        return o;
    };
    float* deg = (float*)(ws + alloc(4 * (size_t)N));   // becomes dis in-place
    int* cnt   = (int*)(ws + alloc(4 * (size_t)N));
    size_t zero_bytes = off;                            // memset deg+cnt
    int* rank  = (int*)(ws + alloc(4 * (size_t)E));
    int* rowp  = (int*)(ws + alloc(4 * (size_t)N));
    int* bsum  = (int*)(ws + alloc(4 * 128));
    unsigned short* AT0 = (unsigned short*)(ws + alloc(2 * 4 * 128 * 160));
    unsigned short* AT1 = (unsigned short*)(ws + alloc(2 * 4 * 128 * 128));
    unsigned short* ATH = (unsigned short*)(ws + alloc(2 * 128 * 128));
    int2* pack = (int2*)(ws + alloc(8 * (size_t)E));
    unsigned short* hb = (unsigned short*)(ws + alloc(2 * (size_t)N * 160));
    unsigned int* za = (unsigned int*)(ws + alloc(2 * (size_t)N * 128));
    unsigned int* zb = (unsigned int*)(ws + alloc(2 * (size_t)N * 128));
    unsigned int* t1 = (unsigned int*)(ws + alloc(2 * (size_t)N * 128));
    unsigned int* t2 = (unsigned int*)(ws + alloc(2 * (size_t)N * 128));

    hipMemsetAsync(ws, 0, zero_bytes, stream);

    dim3 b256(256);
    k_deg_rank<<<dim3((E + 1023) / 1024), b256, 0, stream>>>(src, dst, ew, deg, cnt, rank, E);
    k_dis<<<dim3((N + 255) / 256), b256, 0, stream>>>(deg, N);
    int nb = (N + 1023) / 1024;
    k_blocksum<<<dim3(nb), dim3(1024), 0, stream>>>(cnt, bsum, N);
    k_scan_bsum<<<dim3(1), dim3(128), 0, stream>>>(bsum, nb);
    k_scan<<<dim3(nb), dim3(1024), 0, stream>>>(cnt, bsum, rowp, N);
    k_build_csr<<<dim3((E + 511) / 512), b256, 0, stream>>>(src, dst, ew, deg, rowp, rank, pack, E);
    k_concat<<<dim3((N * 160 + 255) / 256), b256, 0, stream>>>(x, pe, hb, N);
    k_combine<<<dim3((4 * 128 * 160 + 255) / 256), b256, 0, stream>>>(W0, AT0, 144, 160);
    k_combine<<<dim3((4 * 128 * 128 + 255) / 256), b256, 0, stream>>>(W1, AT1, 128, 128);
    k_headsT<<<dim3((128 * 128 + 255) / 256), b256, 0, stream>>>(Wmu, Wlv, ATH);

    dim3 gg((N + 63) / 64, 2);
    dim3 gh((N + 127) / 128, 2);
    dim3 gp((N + 3) / 4);
    const unsigned short* hbu = hb;
    const long long* packll = (const long long*)pack;

    // layer 0 (Horner): h1 = relu(Z0 + P(Z1 + P(Z2 + P Z3)) + b0)
    k_gemm_pair<160><<<gg, b256, 0, stream>>>(hbu, AT0 + 3 * 128 * 160, AT0 + 2 * 128 * 160,
                                              (unsigned short*)za, (unsigned short*)zb, N);   // za=Z3 zb=Z2
    k_prop<0><<<gp, b256, 0, stream>>>(za, zb, t1, nullptr, rowp, packll, N, E);              // t1 = Z2 + P Z3
    k_gemm_pair<160><<<gg, b256, 0, stream>>>(hbu, AT0 + 1 * 128 * 160, AT0 + 0 * 128 * 160,
                                              (unsigned short*)za, (unsigned short*)zb, N);   // za=Z1 zb=Z0
    k_prop<0><<<gp, b256, 0, stream>>>(t1, za, t2, nullptr, rowp, packll, N, E);              // t2 = Z1 + P t1
    k_prop<1><<<gp, b256, 0, stream>>>(t2, zb, t1, b0, rowp, packll, N, E);                   // h1 -> t1

    // layer 1 (input t1, pitch 128)
    const unsigned short* h1 = (const unsigned short*)t1;
    k_gemm_pair<128><<<gg, b256, 0, stream>>>(h1, AT1 + 3 * 128 * 128, AT1 + 2 * 128 * 128,
                                              (unsigned short*)za, (unsigned short*)zb, N);
    k_prop<0><<<gp, b256, 0, stream>>>(za, zb, t2, nullptr, rowp, packll, N, E);
    k_gemm_pair<128><<<gg, b256, 0, stream>>>(h1, AT1 + 1 * 128 * 128, AT1 + 0 * 128 * 128,
                                              (unsigned short*)za, (unsigned short*)zb, N);
    k_prop<0><<<gp, b256, 0, stream>>>(t2, za, t1, nullptr, rowp, packll, N, E);
    k_prop<1><<<gp, b256, 0, stream>>>(t1, zb, t2, b1, rowp, packll, N, E);                   // h2 -> t2

    // heads
    k_gemm_heads<<<gh, b256, 0, stream>>>((const unsigned short*)t2, ATH, (float*)d_out, bmu, blv, N);
}

// Round 4
// 911.958 us; speedup vs baseline: 1.6807x; 1.0722x over previous
//
#include <hip/hip_runtime.h>
#include <hip/hip_bf16.h>

typedef float f32x4 __attribute__((ext_vector_type(4)));
typedef unsigned short u16x8 __attribute__((ext_vector_type(8)));

static __device__ __forceinline__ void mfma16(f32x4& c, const u16x8& a, const u16x8& b) {
    asm("v_mfma_f32_16x16x32_bf16 %0, %1, %2, %0" : "+v"(c) : "v"(a), "v"(b));
}

static __device__ __forceinline__ unsigned short f2bf(float f) {
    __hip_bfloat16 h = __float2bfloat16(f);
    return *reinterpret_cast<unsigned short*>(&h);
}

// ---------------- small prep kernels ----------------

__global__ __launch_bounds__(256) void k_dis(float* deg, int N) {
    int i = blockIdx.x * 256 + threadIdx.x;
    if (i >= N) return;
    float d = deg[i];
    deg[i] = (d > 0.f) ? rsqrtf(d) : 0.f;
}

__global__ __launch_bounds__(1024) void k_blocksum(const int* __restrict__ cnt, int* bsum, int N) {
    __shared__ int sd[1024];
    int i = blockIdx.x * 1024 + threadIdx.x;
    sd[threadIdx.x] = (i < N) ? cnt[i] : 0;
    __syncthreads();
    for (int s = 512; s > 0; s >>= 1) {
        if (threadIdx.x < s) sd[threadIdx.x] += sd[threadIdx.x + s];
        __syncthreads();
    }
    if (threadIdx.x == 0) bsum[blockIdx.x] = sd[0];
}

__global__ __launch_bounds__(128) void k_scan_bsum(int* bsum, int nb) {
    __shared__ int sd[128];
    int t = threadIdx.x;
    int v = (t < nb) ? bsum[t] : 0;
    sd[t] = v;
    __syncthreads();
    for (int d = 1; d < 128; d <<= 1) {
        int x = (t >= d) ? sd[t - d] : 0;
        __syncthreads();
        sd[t] += x;
        __syncthreads();
    }
    if (t < nb) bsum[t] = sd[t] - v;  // exclusive block offsets
}

__global__ __launch_bounds__(1024) void k_scan(const int* __restrict__ cnt, const int* __restrict__ bsum,
                                               int* rowp, int N) {
    __shared__ int sd[1024];
    int i = blockIdx.x * 1024 + threadIdx.x;
    int v = (i < N) ? cnt[i] : 0;
    sd[threadIdx.x] = v;
    __syncthreads();
    for (int d = 1; d < 1024; d <<= 1) {
        int x = (threadIdx.x >= d) ? sd[threadIdx.x - d] : 0;
        __syncthreads();
        sd[threadIdx.x] += x;
        __syncthreads();
    }
    if (i < N) rowp[i] = sd[threadIdx.x] - v + bsum[blockIdx.x];
}

// atomic-free CSR fill: pos = rowp[dst] + rank (u8)
__global__ __launch_bounds__(256) void k_build_csr(const int* __restrict__ src, const int* __restrict__ dst,
                                                   const float* __restrict__ ew, const float* __restrict__ dis,
                                                   const int* __restrict__ rowp,
                                                   const unsigned char* __restrict__ rank,
                                                   int2* __restrict__ pack, int E) {
    int base = blockIdx.x * 512 + threadIdx.x;
#pragma unroll
    for (int u = 0; u < 2; u++) {
        int e = base + u * 256;
        if (e < E) {
            int s = src[e], d = dst[e];
            float w = (s == d) ? 0.f : ew[e];
            float wh = -dis[s] * w * dis[d];
            int pos = rowp[d] + (int)rank[e];
            int2 p;
            p.x = s;
            p.y = __float_as_int(wh);
            pack[pos] = p;
        }
    }
}

// ---------------- weight prep ----------------

// AT[sel][n][kk] = A_sel[kk][n] (transposed, bf16), A0=W0-W2, A1=W1-3W3, A2=2W2, A3=4W3
__global__ __launch_bounds__(256) void k_combine(const float* __restrict__ W, unsigned short* __restrict__ AT,
                                                 int D, int KPAD) {
    int i = blockIdx.x * 256 + threadIdx.x;
    int tot = 4 * 128 * KPAD;
    if (i >= tot) return;
    int sel = i / (128 * KPAD);
    int rem = i - sel * 128 * KPAD;
    int n = rem / KPAD;
    int kk = rem - n * KPAD;
    float v = 0.f;
    if (kk < D) {
        if (sel == 0)      v = W[(0 * D + kk) * 128 + n] - W[(2 * D + kk) * 128 + n];
        else if (sel == 1) v = W[(1 * D + kk) * 128 + n] - 3.f * W[(3 * D + kk) * 128 + n];
        else if (sel == 2) v = 2.f * W[(2 * D + kk) * 128 + n];
        else               v = 4.f * W[(3 * D + kk) * 128 + n];
    }
    AT[i] = f2bf(v);
}

__global__ __launch_bounds__(256) void k_headsT(const float* __restrict__ Wmu, const float* __restrict__ Wlv,
                                                unsigned short* __restrict__ AT) {
    int i = blockIdx.x * 256 + threadIdx.x;
    if (i >= 128 * 128) return;
    int n = i >> 7, kk = i & 127;
    float v = (n < 64) ? Wmu[kk * 64 + n] : Wlv[kk * 64 + (n - 64)];
    AT[i] = f2bf(v);
}

// ---------------- pair GEMM device body ----------------
// SRC=0: A from bf16 buffer pitch KPAD. SRC=1: A = concat(x f32 [128], pe f32 [16], pad) -> bf16.

template <int KPAD, int SRC>
static __device__ __forceinline__ void gemm_pair_body(const unsigned short* __restrict__ Abf,
                                                      const float* __restrict__ x,
                                                      const float* __restrict__ pe,
                                                      const unsigned short* __restrict__ Bta,
                                                      const unsigned short* __restrict__ Btb,
                                                      unsigned short* __restrict__ outA,
                                                      unsigned short* __restrict__ outB,
                                                      int N, int bx, int bn,
                                                      unsigned short* As, unsigned short* Bs) {
    constexpr int LP = KPAD + 8;
    const int tid = threadIdx.x;
    const int row0 = bx * 64;

    {   // stage A tile (64 x KPAD)
        constexpr int TOT = 64 * KPAD;
        for (int c = tid * 8; c < TOT; c += 256 * 8) {
            int r = c / KPAD;
            int k = c - r * KPAD;
            int gr = row0 + r;
            if (gr > N - 1) gr = N - 1;
            u16x8 v;
            if (SRC == 0) {
                v = *reinterpret_cast<const u16x8*>(&Abf[(size_t)gr * KPAD + k]);
            } else {
                if (k < 128) {
                    float4 f0 = *reinterpret_cast<const float4*>(&x[(size_t)gr * 128 + k]);
                    float4 f1 = *reinterpret_cast<const float4*>(&x[(size_t)gr * 128 + k + 4]);
                    v[0] = f2bf(f0.x); v[1] = f2bf(f0.y); v[2] = f2bf(f0.z); v[3] = f2bf(f0.w);
                    v[4] = f2bf(f1.x); v[5] = f2bf(f1.y); v[6] = f2bf(f1.z); v[7] = f2bf(f1.w);
                } else if (k < 144) {
                    float4 f0 = *reinterpret_cast<const float4*>(&pe[(size_t)gr * 16 + (k - 128)]);
                    float4 f1 = *reinterpret_cast<const float4*>(&pe[(size_t)gr * 16 + (k - 124)]);
                    v[0] = f2bf(f0.x); v[1] = f2bf(f0.y); v[2] = f2bf(f0.z); v[3] = f2bf(f0.w);
                    v[4] = f2bf(f1.x); v[5] = f2bf(f1.y); v[6] = f2bf(f1.z); v[7] = f2bf(f1.w);
                } else {
                    v = (u16x8){0, 0, 0, 0, 0, 0, 0, 0};
                }
            }
            *reinterpret_cast<u16x8*>(&As[r * LP + k]) = v;
        }
    }
    {   // stage B tiles: rows 0..63 = Bta cols [bn*64..), rows 64..127 = Btb
        constexpr int TOT = 128 * KPAD;
        for (int c = tid * 8; c < TOT; c += 256 * 8) {
            int r = c / KPAD;
            int k = c - r * KPAD;
            const unsigned short* srcp = (r < 64) ? &Bta[(size_t)(bn * 64 + r) * KPAD + k]
                                                  : &Btb[(size_t)(bn * 64 + r - 64) * KPAD + k];
            u16x8 v = *reinterpret_cast<const u16x8*>(srcp);
            *reinterpret_cast<u16x8*>(&Bs[r * LP + k]) = v;
        }
    }
    __syncthreads();

    const int wave = tid >> 6, lane = tid & 63;
    const int wm = wave >> 1, wn = wave & 1;
    const int lr = lane & 15, lg = lane >> 4;

    f32x4 acc[2][4];
#pragma unroll
    for (int i = 0; i < 2; i++)
#pragma unroll
        for (int j = 0; j < 4; j++) acc[i][j] = (f32x4){0.f, 0.f, 0.f, 0.f};

    asm volatile("s_nop 7"
                 : "+v"(acc[0][0]), "+v"(acc[0][1]), "+v"(acc[0][2]), "+v"(acc[0][3]),
                   "+v"(acc[1][0]), "+v"(acc[1][1]), "+v"(acc[1][2]), "+v"(acc[1][3]));

    constexpr int KS = KPAD / 32;
#pragma unroll
    for (int ks = 0; ks < KS; ks++) {
        u16x8 a[2], b[4];
#pragma unroll
        for (int fm = 0; fm < 2; fm++)
            a[fm] = *reinterpret_cast<const u16x8*>(&As[(wm * 32 + fm * 16 + lr) * LP + ks * 32 + lg * 8]);
#pragma unroll
        for (int fn = 0; fn < 4; fn++)
            b[fn] = *reinterpret_cast<const u16x8*>(&Bs[(wn * 64 + fn * 16 + lr) * LP + ks * 32 + lg * 8]);
#pragma unroll
        for (int fm = 0; fm < 2; fm++)
#pragma unroll
            for (int fn = 0; fn < 4; fn++) mfma16(acc[fm][fn], a[fm], b[fn]);
    }

    asm volatile("s_nop 7\n\ts_nop 7\n\ts_nop 7"
                 : "+v"(acc[0][0]), "+v"(acc[0][1]), "+v"(acc[0][2]), "+v"(acc[0][3]),
                   "+v"(acc[1][0]), "+v"(acc[1][1]), "+v"(acc[1][2]), "+v"(acc[1][3]));

    unsigned short* outp = (wn == 0) ? outA : outB;
#pragma unroll
    for (int fm = 0; fm < 2; fm++)
#pragma unroll
        for (int fn = 0; fn < 4; fn++)
#pragma unroll
            for (int i = 0; i < 4; i++) {
                int r = row0 + wm * 32 + fm * 16 + lg * 4 + i;
                if (r < N) {
                    int c = bn * 64 + fn * 16 + lr;
                    outp[(size_t)r * 128 + c] = f2bf(acc[fm][fn][i]);
                }
            }
}

// standalone pair GEMM (layer 1, bf16 source)
__global__ __launch_bounds__(256) void k_gemm_pair128(const unsigned short* __restrict__ Abf,
                                                      const unsigned short* __restrict__ Bta,
                                                      const unsigned short* __restrict__ Btb,
                                                      unsigned short* __restrict__ outA,
                                                      unsigned short* __restrict__ outB,
                                                      int N) {
    __shared__ __align__(16) unsigned short As[64 * 136];
    __shared__ __align__(16) unsigned short Bs[128 * 136];
    gemm_pair_body<128, 0>(Abf, nullptr, nullptr, Bta, Btb, outA, outB, N,
                           blockIdx.x, blockIdx.y, As, Bs);
}

// ---------------- K1 mega: striped {deg/cnt/rank atomics} | {layer-0 pair GEMMs w/ fused concat} ----------------

__global__ __launch_bounds__(256) void k_mega(const int* __restrict__ src, const int* __restrict__ dst,
                                              const float* __restrict__ ew,
                                              float* deg, int* cnt, unsigned char* __restrict__ rank,
                                              const float* __restrict__ x, const float* __restrict__ pe,
                                              const unsigned short* __restrict__ AT0,
                                              unsigned short* __restrict__ oZ3, unsigned short* __restrict__ oZ2,
                                              unsigned short* __restrict__ oZ1, unsigned short* __restrict__ oZ0,
                                              int N, int E, int Ga, int Gp1) {
    __shared__ __align__(16) unsigned short As[64 * 168];
    __shared__ __align__(16) unsigned short Bs[128 * 168];
    const int bid = blockIdx.x;
    int gemm_id;
    if (bid < 2 * Ga) {
        if ((bid & 1) == 0) {
            // atomic block: 256 edges, 1 per thread (round-1 style)
            int e = (bid >> 1) * 256 + threadIdx.x;
            if (e < E) {
                int s = src[e], d = dst[e];
                float w = (s == d) ? 0.f : ew[e];
                atomicAdd(&deg[s], w);
                rank[e] = (unsigned char)atomicAdd(&cnt[d], 1);
            }
            return;
        }
        gemm_id = bid >> 1;
    } else {
        gemm_id = bid - Ga;
    }
    // gemm block
    int P = (gemm_id < Gp1) ? 0 : 1;
    int sub = gemm_id - P * Gp1;
    int bx = sub >> 1, bn = sub & 1;
    const unsigned short* Bta = AT0 + (size_t)(3 - 2 * P) * 128 * 160;
    const unsigned short* Btb = AT0 + (size_t)(2 - 2 * P) * 128 * 160;
    unsigned short* outA = (P == 0) ? oZ3 : oZ1;
    unsigned short* outB = (P == 0) ? oZ2 : oZ0;
    gemm_pair_body<160, 1>(nullptr, x, pe, Bta, Btb, outA, outB, N, bx, bn, As, Bs);
}

// ---------------- heads GEMM: [mu|logvar](f32) = h(bf16) @ ATH^T + bias ----------------

__global__ __launch_bounds__(256) void k_gemm_heads(const unsigned short* __restrict__ Abf,
                                                    const unsigned short* __restrict__ Bt,
                                                    float* __restrict__ out,
                                                    const float* __restrict__ bmu, const float* __restrict__ blv,
                                                    int N) {
    constexpr int KPAD = 128;
    constexpr int LP = KPAD + 8;
    __shared__ __align__(16) unsigned short As[128 * LP];
    __shared__ __align__(16) unsigned short Bs[64 * LP];
    const int tid = threadIdx.x;
    const int row0 = blockIdx.x * 128;
    const int bn = blockIdx.y;

    {
        constexpr int TOT = 128 * KPAD;
        for (int c = tid * 8; c < TOT; c += 256 * 8) {
            int r = c / KPAD;
            int k = c - r * KPAD;
            int gr = row0 + r;
            if (gr > N - 1) gr = N - 1;
            u16x8 v = *reinterpret_cast<const u16x8*>(&Abf[(size_t)gr * KPAD + k]);
            *reinterpret_cast<u16x8*>(&As[r * LP + k]) = v;
        }
    }
    {
        constexpr int TOT = 64 * KPAD;
        for (int c = tid * 8; c < TOT; c += 256 * 8) {
            int r = c / KPAD;
            int k = c - r * KPAD;
            u16x8 v = *reinterpret_cast<const u16x8*>(&Bt[(size_t)(bn * 64 + r) * KPAD + k]);
            *reinterpret_cast<u16x8*>(&Bs[r * LP + k]) = v;
        }
    }
    __syncthreads();

    const int wave = tid >> 6, lane = tid & 63;
    const int wm = wave >> 1, wn = wave & 1;
    const int lr = lane & 15, lg = lane >> 4;

    f32x4 acc[4][2];
#pragma unroll
    for (int i = 0; i < 4; i++)
#pragma unroll
        for (int j = 0; j < 2; j++) acc[i][j] = (f32x4){0.f, 0.f, 0.f, 0.f};

    asm volatile("s_nop 7"
                 : "+v"(acc[0][0]), "+v"(acc[0][1]), "+v"(acc[1][0]), "+v"(acc[1][1]),
                   "+v"(acc[2][0]), "+v"(acc[2][1]), "+v"(acc[3][0]), "+v"(acc[3][1]));

#pragma unroll
    for (int ks = 0; ks < KPAD / 32; ks++) {
        u16x8 a[4], b[2];
#pragma unroll
        for (int fm = 0; fm < 4; fm++)
            a[fm] = *reinterpret_cast<const u16x8*>(&As[(wm * 64 + fm * 16 + lr) * LP + ks * 32 + lg * 8]);
#pragma unroll
        for (int fn = 0; fn < 2; fn++)
            b[fn] = *reinterpret_cast<const u16x8*>(&Bs[(wn * 32 + fn * 16 + lr) * LP + ks * 32 + lg * 8]);
#pragma unroll
        for (int fm = 0; fm < 4; fm++)
#pragma unroll
            for (int fn = 0; fn < 2; fn++) mfma16(acc[fm][fn], a[fm], b[fn]);
    }

    asm volatile("s_nop 7\n\ts_nop 7\n\ts_nop 7"
                 : "+v"(acc[0][0]), "+v"(acc[0][1]), "+v"(acc[1][0]), "+v"(acc[1][1]),
                   "+v"(acc[2][0]), "+v"(acc[2][1]), "+v"(acc[3][0]), "+v"(acc[3][1]));

#pragma unroll
    for (int fm = 0; fm < 4; fm++)
#pragma unroll
        for (int fn = 0; fn < 2; fn++)
#pragma unroll
            for (int i = 0; i < 4; i++) {
                int r = row0 + wm * 64 + fm * 16 + lg * 4 + i;
                if (r < N) {
                    int c = bn * 64 + wn * 32 + fn * 16 + lr;
                    if (c < 64) out[(size_t)r * 64 + c] = acc[fm][fn][i] + bmu[c];
                    else out[(size_t)N * 64 + (size_t)r * 64 + (c - 64)] = acc[fm][fn][i] + blv[c - 64];
                }
            }
}

// ---------------- sparse prop: tout = [relu](z + P*tin [+ bias])  — all bf16, fp32 accum ----------------

template <int MODE>  // 0: plain ; 1: + bias, relu
__global__ __launch_bounds__(256) void k_prop(const unsigned int* __restrict__ tin,
                                              const unsigned int* __restrict__ z,
                                              unsigned int* __restrict__ tout,
                                              const float* __restrict__ bias,
                                              const int* __restrict__ rowp,
                                              const long long* __restrict__ pack,
                                              int N, int E) {
    int wave = threadIdx.x >> 6, lane = threadIdx.x & 63;
    int node = blockIdx.x * 4 + wave;
    if (node >= N) return;
    int beg = rowp[node];
    int end = (node == N - 1) ? E : rowp[node + 1];
    float ax = 0.f, ay = 0.f;
    int e = beg;
    for (; e + 3 < end; e += 4) {
        long long q0 = __builtin_nontemporal_load(pack + e);
        long long q1 = __builtin_nontemporal_load(pack + e + 1);
        long long q2 = __builtin_nontemporal_load(pack + e + 2);
        long long q3 = __builtin_nontemporal_load(pack + e + 3);
        unsigned int v0 = tin[(size_t)(unsigned int)q0 * 64 + lane];
        unsigned int v1 = tin[(size_t)(unsigned int)q1 * 64 + lane];
        unsigned int v2 = tin[(size_t)(unsigned int)q2 * 64 + lane];
        unsigned int v3 = tin[(size_t)(unsigned int)q3 * 64 + lane];
        float w0 = __uint_as_float((unsigned int)((unsigned long long)q0 >> 32));
        float w1 = __uint_as_float((unsigned int)((unsigned long long)q1 >> 32));
        float w2 = __uint_as_float((unsigned int)((unsigned long long)q2 >> 32));
        float w3 = __uint_as_float((unsigned int)((unsigned long long)q3 >> 32));
        ax = fmaf(w0, __uint_as_float(v0 << 16), ax);
        ay = fmaf(w0, __uint_as_float(v0 & 0xffff0000u), ay);
        ax = fmaf(w1, __uint_as_float(v1 << 16), ax);
        ay = fmaf(w1, __uint_as_float(v1 & 0xffff0000u), ay);
        ax = fmaf(w2, __uint_as_float(v2 << 16), ax);
        ay = fmaf(w2, __uint_as_float(v2 & 0xffff0000u), ay);
        ax = fmaf(w3, __uint_as_float(v3 << 16), ax);
        ay = fmaf(w3, __uint_as_float(v3 & 0xffff0000u), ay);
    }
    for (; e < end; e++) {
        long long q0 = __builtin_nontemporal_load(pack + e);
        unsigned int v0 = tin[(size_t)(unsigned int)q0 * 64 + lane];
        float w0 = __uint_as_float((unsigned int)((unsigned long long)q0 >> 32));
        ax = fmaf(w0, __uint_as_float(v0 << 16), ax);
        ay = fmaf(w0, __uint_as_float(v0 & 0xffff0000u), ay);
    }
    unsigned int zv = __builtin_nontemporal_load(z + (size_t)node * 64 + lane);
    float rx = __uint_as_float(zv << 16) + ax;
    float ry = __uint_as_float(zv & 0xffff0000u) + ay;
    if (MODE == 1) {
        rx = fmaxf(rx + bias[lane * 2], 0.f);
        ry = fmaxf(ry + bias[lane * 2 + 1], 0.f);
    }
    unsigned int lo = f2bf(rx), hi = f2bf(ry);
    tout[(size_t)node * 64 + lane] = lo | (hi << 16);
}

// ---------------- launch ----------------

extern "C" void kernel_launch(void* const* d_in, const int* in_sizes, int n_in,
                              void* d_out, int out_size, void* d_ws, size_t ws_size,
                              hipStream_t stream) {
    const float* x   = (const float*)d_in[0];
    const int*   ei  = (const int*)d_in[1];
    const float* pe  = (const float*)d_in[2];
    const float* ew  = (const float*)d_in[3];
    const float* W0  = (const float*)d_in[4];
    const float* b0  = (const float*)d_in[5];
    const float* W1  = (const float*)d_in[6];
    const float* b1  = (const float*)d_in[7];
    const float* Wmu = (const float*)d_in[8];
    const float* bmu = (const float*)d_in[9];
    const float* Wlv = (const float*)d_in[10];
    const float* blv = (const float*)d_in[11];

    const int N = in_sizes[0] / 128;
    const int E = in_sizes[3];
    const int* src = ei;
    const int* dst = ei + E;

    char* ws = (char*)d_ws;
    size_t off = 0;
    auto alloc = [&](size_t bytes) {
        size_t o = off;
        off += (bytes + 1023) & ~(size_t)1023;
        return o;
    };
    float* deg = (float*)(ws + alloc(4 * (size_t)N));   // becomes dis in-place
    int* cnt   = (int*)(ws + alloc(4 * (size_t)N));
    size_t zero_bytes = off;                            // memset deg+cnt
    unsigned char* rank = (unsigned char*)(ws + alloc((size_t)E));
    int* rowp  = (int*)(ws + alloc(4 * (size_t)N));
    int* bsum  = (int*)(ws + alloc(4 * 128));
    unsigned short* AT0 = (unsigned short*)(ws + alloc(2 * 4 * 128 * 160));
    unsigned short* AT1 = (unsigned short*)(ws + alloc(2 * 4 * 128 * 128));
    unsigned short* ATH = (unsigned short*)(ws + alloc(2 * 128 * 128));
    int2* pack = (int2*)(ws + alloc(8 * (size_t)E));
    unsigned int* B1 = (unsigned int*)(ws + alloc(2 * (size_t)N * 128));
    unsigned int* B2 = (unsigned int*)(ws + alloc(2 * (size_t)N * 128));
    unsigned int* B3 = (unsigned int*)(ws + alloc(2 * (size_t)N * 128));
    unsigned int* B4 = (unsigned int*)(ws + alloc(2 * (size_t)N * 128));
    unsigned int* B5 = (unsigned int*)(ws + alloc(2 * (size_t)N * 128));

    hipMemsetAsync(ws, 0, zero_bytes, stream);

    dim3 b256(256);
    // weight prep (K1's gemm blocks read AT0)
    k_combine<<<dim3((4 * 128 * 160 + 255) / 256), b256, 0, stream>>>(W0, AT0, 144, 160);
    k_combine<<<dim3((4 * 128 * 128 + 255) / 256), b256, 0, stream>>>(W1, AT1, 128, 128);
    k_headsT<<<dim3((128 * 128 + 255) / 256), b256, 0, stream>>>(Wmu, Wlv, ATH);

    // K1: striped atomics + layer-0 pair GEMMs (fused concat)
    int Ga = (E + 255) / 256;
    int Gp1 = ((N + 63) / 64) * 2;
    int Gg = 2 * Gp1;
    // require Gg >= Ga for the decode (holds: 6252 >= 6250); if not, pad atomics handle E-bound anyway
    int total = (Ga <= Gg) ? (Ga + Gg) : (2 * Ga);  // decode assumes bid<2*Ga split
    k_mega<<<dim3(total), b256, 0, stream>>>(src, dst, ew, deg, cnt, rank, x, pe, AT0,
                                             (unsigned short*)B1, (unsigned short*)B2,
                                             (unsigned short*)B3, (unsigned short*)B4,
                                             N, E, Ga, Gp1);

    k_dis<<<dim3((N + 255) / 256), b256, 0, stream>>>(deg, N);
    int nb = (N + 1023) / 1024;
    k_blocksum<<<dim3(nb), dim3(1024), 0, stream>>>(cnt, bsum, N);
    k_scan_bsum<<<dim3(1), dim3(128), 0, stream>>>(bsum, nb);
    k_scan<<<dim3(nb), dim3(1024), 0, stream>>>(cnt, bsum, rowp, N);
    k_build_csr<<<dim3((E + 511) / 512), b256, 0, stream>>>(src, dst, ew, deg, rowp, rank, pack, E);

    dim3 gg((N + 63) / 64, 2);
    dim3 gh((N + 127) / 128, 2);
    dim3 gp((N + 3) / 4);
    const long long* packll = (const long long*)pack;

    // layer 0 (Horner): B1=Z3 B2=Z2 B3=Z1 B4=Z0 (from K1)
    k_prop<0><<<gp, b256, 0, stream>>>(B1, B2, B5, nullptr, rowp, packll, N, E);   // B5 = Z2 + P Z3
    k_prop<0><<<gp, b256, 0, stream>>>(B5, B3, B1, nullptr, rowp, packll, N, E);   // B1 = Z1 + P B5
    k_prop<1><<<gp, b256, 0, stream>>>(B1, B4, B2, b0, rowp, packll, N, E);        // B2 = h1

    // layer 1
    const unsigned short* h1 = (const unsigned short*)B2;
    k_gemm_pair128<<<gg, b256, 0, stream>>>(h1, AT1 + 3 * 128 * 128, AT1 + 2 * 128 * 128,
                                            (unsigned short*)B3, (unsigned short*)B4, N);  // Z3' Z2'
    k_gemm_pair128<<<gg, b256, 0, stream>>>(h1, AT1 + 1 * 128 * 128, AT1 + 0 * 128 * 128,
                                            (unsigned short*)B1, (unsigned short*)B5, N);  // Z1' Z0'
    k_prop<0><<<gp, b256, 0, stream>>>(B3, B4, B2, nullptr, rowp, packll, N, E);   // B2 = Z2' + P Z3'
    k_prop<0><<<gp, b256, 0, stream>>>(B2, B1, B3, nullptr, rowp, packll, N, E);   // B3 = Z1' + P B2
    k_prop<1><<<gp, b256, 0, stream>>>(B3, B5, B4, b1, rowp, packll, N, E);        // B4 = h2

    // heads
    k_gemm_heads<<<gh, b256, 0, stream>>>((const unsigned short*)B4, ATH, (float*)d_out, bmu, blv, N);
}

// Round 5
// 895.210 us; speedup vs baseline: 1.7122x; 1.0187x over previous
//
#include <hip/hip_runtime.h>
#include <hip/hip_bf16.h>

typedef float f32x4 __attribute__((ext_vector_type(4)));
typedef unsigned short u16x8 __attribute__((ext_vector_type(8)));

static __device__ __forceinline__ void mfma16(f32x4& c, const u16x8& a, const u16x8& b) {
    asm("v_mfma_f32_16x16x32_bf16 %0, %1, %2, %0" : "+v"(c) : "v"(a), "v"(b));
}

static __device__ __forceinline__ unsigned short f2bf(float f) {
    __hip_bfloat16 h = __float2bfloat16(f);
    return *reinterpret_cast<unsigned short*>(&h);
}

// ---------------- small prep kernels ----------------

__global__ __launch_bounds__(256) void k_dis(float* deg, int N) {
    int i = blockIdx.x * 256 + threadIdx.x;
    if (i >= N) return;
    float d = deg[i];
    deg[i] = (d > 0.f) ? rsqrtf(d) : 0.f;
}

__global__ __launch_bounds__(1024) void k_blocksum(const int* __restrict__ cnt, int* bsum, int N) {
    __shared__ int sd[1024];
    int i = blockIdx.x * 1024 + threadIdx.x;
    sd[threadIdx.x] = (i < N) ? cnt[i] : 0;
    __syncthreads();
    for (int s = 512; s > 0; s >>= 1) {
        if (threadIdx.x < s) sd[threadIdx.x] += sd[threadIdx.x + s];
        __syncthreads();
    }
    if (threadIdx.x == 0) bsum[blockIdx.x] = sd[0];
}

__global__ __launch_bounds__(128) void k_scan_bsum(int* bsum, int nb) {
    __shared__ int sd[128];
    int t = threadIdx.x;
    int v = (t < nb) ? bsum[t] : 0;
    sd[t] = v;
    __syncthreads();
    for (int d = 1; d < 128; d <<= 1) {
        int x = (t >= d) ? sd[t - d] : 0;
        __syncthreads();
        sd[t] += x;
        __syncthreads();
    }
    if (t < nb) bsum[t] = sd[t] - v;  // exclusive block offsets
}

__global__ __launch_bounds__(1024) void k_scan(const int* __restrict__ cnt, const int* __restrict__ bsum,
                                               int* rowp, int N) {
    __shared__ int sd[1024];
    int i = blockIdx.x * 1024 + threadIdx.x;
    int v = (i < N) ? cnt[i] : 0;
    sd[threadIdx.x] = v;
    __syncthreads();
    for (int d = 1; d < 1024; d <<= 1) {
        int x = (threadIdx.x >= d) ? sd[threadIdx.x - d] : 0;
        __syncthreads();
        sd[threadIdx.x] += x;
        __syncthreads();
    }
    if (i < N) rowp[i] = sd[threadIdx.x] - v + bsum[blockIdx.x];
}

// atomic-free CSR fill: pos = rowp[dst] + rank (u8)
__global__ __launch_bounds__(256) void k_build_csr(const int* __restrict__ src, const int* __restrict__ dst,
                                                   const float* __restrict__ ew, const float* __restrict__ dis,
                                                   const int* __restrict__ rowp,
                                                   const unsigned char* __restrict__ rank,
                                                   int2* __restrict__ pack, int E) {
    int base = blockIdx.x * 512 + threadIdx.x;
#pragma unroll
    for (int u = 0; u < 2; u++) {
        int e = base + u * 256;
        if (e < E) {
            int s = src[e], d = dst[e];
            float w = (s == d) ? 0.f : ew[e];
            float wh = -dis[s] * w * dis[d];
            int pos = rowp[d] + (int)rank[e];
            int2 p;
            p.x = s;
            p.y = __float_as_int(wh);
            pack[pos] = p;
        }
    }
}

// ---------------- weight prep ----------------

// AT[sel][n][kk] = A_sel[kk][n] (transposed, bf16), A0=W0-W2, A1=W1-3W3, A2=2W2, A3=4W3
__global__ __launch_bounds__(256) void k_combine(const float* __restrict__ W, unsigned short* __restrict__ AT,
                                                 int D, int KPAD) {
    int i = blockIdx.x * 256 + threadIdx.x;
    int tot = 4 * 128 * KPAD;
    if (i >= tot) return;
    int sel = i / (128 * KPAD);
    int rem = i - sel * 128 * KPAD;
    int n = rem / KPAD;
    int kk = rem - n * KPAD;
    float v = 0.f;
    if (kk < D) {
        if (sel == 0)      v = W[(0 * D + kk) * 128 + n] - W[(2 * D + kk) * 128 + n];
        else if (sel == 1) v = W[(1 * D + kk) * 128 + n] - 3.f * W[(3 * D + kk) * 128 + n];
        else if (sel == 2) v = 2.f * W[(2 * D + kk) * 128 + n];
        else               v = 4.f * W[(3 * D + kk) * 128 + n];
    }
    AT[i] = f2bf(v);
}

__global__ __launch_bounds__(256) void k_headsT(const float* __restrict__ Wmu, const float* __restrict__ Wlv,
                                                unsigned short* __restrict__ AT) {
    int i = blockIdx.x * 256 + threadIdx.x;
    if (i >= 128 * 128) return;
    int n = i >> 7, kk = i & 127;
    float v = (n < 64) ? Wmu[kk * 64 + n] : Wlv[kk * 64 + (n - 64)];
    AT[i] = f2bf(v);
}

// ---------------- pair GEMM device body ----------------
// SRC=0: A from bf16 buffer pitch KPAD. SRC=1: A = concat(x f32 [128], pe f32 [16], pad) -> bf16.

template <int KPAD, int SRC>
static __device__ __forceinline__ void gemm_pair_body(const unsigned short* __restrict__ Abf,
                                                      const float* __restrict__ x,
                                                      const float* __restrict__ pe,
                                                      const unsigned short* __restrict__ Bta,
                                                      const unsigned short* __restrict__ Btb,
                                                      unsigned short* __restrict__ outA,
                                                      unsigned short* __restrict__ outB,
                                                      int N, int bx, int bn,
                                                      unsigned short* As, unsigned short* Bs) {
    constexpr int LP = KPAD + 8;
    const int tid = threadIdx.x;
    const int row0 = bx * 64;

    {   // stage A tile (64 x KPAD)
        constexpr int TOT = 64 * KPAD;
        for (int c = tid * 8; c < TOT; c += 256 * 8) {
            int r = c / KPAD;
            int k = c - r * KPAD;
            int gr = row0 + r;
            if (gr > N - 1) gr = N - 1;
            u16x8 v;
            if (SRC == 0) {
                v = *reinterpret_cast<const u16x8*>(&Abf[(size_t)gr * KPAD + k]);
            } else {
                if (k < 128) {
                    float4 f0 = *reinterpret_cast<const float4*>(&x[(size_t)gr * 128 + k]);
                    float4 f1 = *reinterpret_cast<const float4*>(&x[(size_t)gr * 128 + k + 4]);
                    v[0] = f2bf(f0.x); v[1] = f2bf(f0.y); v[2] = f2bf(f0.z); v[3] = f2bf(f0.w);
                    v[4] = f2bf(f1.x); v[5] = f2bf(f1.y); v[6] = f2bf(f1.z); v[7] = f2bf(f1.w);
                } else if (k < 144) {
                    float4 f0 = *reinterpret_cast<const float4*>(&pe[(size_t)gr * 16 + (k - 128)]);
                    float4 f1 = *reinterpret_cast<const float4*>(&pe[(size_t)gr * 16 + (k - 124)]);
                    v[0] = f2bf(f0.x); v[1] = f2bf(f0.y); v[2] = f2bf(f0.z); v[3] = f2bf(f0.w);
                    v[4] = f2bf(f1.x); v[5] = f2bf(f1.y); v[6] = f2bf(f1.z); v[7] = f2bf(f1.w);
                } else {
                    v = (u16x8){0, 0, 0, 0, 0, 0, 0, 0};
                }
            }
            *reinterpret_cast<u16x8*>(&As[r * LP + k]) = v;
        }
    }
    {   // stage B tiles: rows 0..63 = Bta cols [bn*64..), rows 64..127 = Btb
        constexpr int TOT = 128 * KPAD;
        for (int c = tid * 8; c < TOT; c += 256 * 8) {
            int r = c / KPAD;
            int k = c - r * KPAD;
            const unsigned short* srcp = (r < 64) ? &Bta[(size_t)(bn * 64 + r) * KPAD + k]
                                                  : &Btb[(size_t)(bn * 64 + r - 64) * KPAD + k];
            u16x8 v = *reinterpret_cast<const u16x8*>(srcp);
            *reinterpret_cast<u16x8*>(&Bs[r * LP + k]) = v;
        }
    }
    __syncthreads();

    const int wave = tid >> 6, lane = tid & 63;
    const int wm = wave >> 1, wn = wave & 1;
    const int lr = lane & 15, lg = lane >> 4;

    f32x4 acc[2][4];
#pragma unroll
    for (int i = 0; i < 2; i++)
#pragma unroll
        for (int j = 0; j < 4; j++) acc[i][j] = (f32x4){0.f, 0.f, 0.f, 0.f};

    asm volatile("s_nop 7"
                 : "+v"(acc[0][0]), "+v"(acc[0][1]), "+v"(acc[0][2]), "+v"(acc[0][3]),
                   "+v"(acc[1][0]), "+v"(acc[1][1]), "+v"(acc[1][2]), "+v"(acc[1][3]));

    constexpr int KS = KPAD / 32;
#pragma unroll
    for (int ks = 0; ks < KS; ks++) {
        u16x8 a[2], b[4];
#pragma unroll
        for (int fm = 0; fm < 2; fm++)
            a[fm] = *reinterpret_cast<const u16x8*>(&As[(wm * 32 + fm * 16 + lr) * LP + ks * 32 + lg * 8]);
#pragma unroll
        for (int fn = 0; fn < 4; fn++)
            b[fn] = *reinterpret_cast<const u16x8*>(&Bs[(wn * 64 + fn * 16 + lr) * LP + ks * 32 + lg * 8]);
#pragma unroll
        for (int fm = 0; fm < 2; fm++)
#pragma unroll
            for (int fn = 0; fn < 4; fn++) mfma16(acc[fm][fn], a[fm], b[fn]);
    }

    asm volatile("s_nop 7\n\ts_nop 7\n\ts_nop 7"
                 : "+v"(acc[0][0]), "+v"(acc[0][1]), "+v"(acc[0][2]), "+v"(acc[0][3]),
                   "+v"(acc[1][0]), "+v"(acc[1][1]), "+v"(acc[1][2]), "+v"(acc[1][3]));

    unsigned short* outp = (wn == 0) ? outA : outB;
#pragma unroll
    for (int fm = 0; fm < 2; fm++)
#pragma unroll
        for (int fn = 0; fn < 4; fn++)
#pragma unroll
            for (int i = 0; i < 4; i++) {
                int r = row0 + wm * 32 + fm * 16 + lg * 4 + i;
                if (r < N) {
                    int c = bn * 64 + fn * 16 + lr;
                    outp[(size_t)r * 128 + c] = f2bf(acc[fm][fn][i]);
                }
            }
}

// layer-1: both pairs in one launch. grid = ((N+63)/64, 2, 2); z picks pair P.
__global__ __launch_bounds__(256) void k_gemm_pair128(const unsigned short* __restrict__ Abf,
                                                      const unsigned short* __restrict__ AT1,
                                                      unsigned short* __restrict__ oZ3,
                                                      unsigned short* __restrict__ oZ2,
                                                      unsigned short* __restrict__ oZ1,
                                                      unsigned short* __restrict__ oZ0,
                                                      int N) {
    __shared__ __align__(16) unsigned short As[64 * 136];
    __shared__ __align__(16) unsigned short Bs[128 * 136];
    const int P = blockIdx.z;
    const unsigned short* Bta = AT1 + (size_t)(3 - 2 * P) * 128 * 128;
    const unsigned short* Btb = AT1 + (size_t)(2 - 2 * P) * 128 * 128;
    unsigned short* outA = (P == 0) ? oZ3 : oZ1;
    unsigned short* outB = (P == 0) ? oZ2 : oZ0;
    gemm_pair_body<128, 0>(Abf, nullptr, nullptr, Bta, Btb, outA, outB, N,
                           blockIdx.x, blockIdx.y, As, Bs);
}

// ---------------- K1 mega: EVERY block = {256-edge atomic chunk} then {layer-0 pair-GEMM tile} ----------------

__global__ __launch_bounds__(256) void k_mega(const int* __restrict__ src, const int* __restrict__ dst,
                                              const float* __restrict__ ew,
                                              float* deg, int* cnt, unsigned char* __restrict__ rank,
                                              const float* __restrict__ x, const float* __restrict__ pe,
                                              const unsigned short* __restrict__ AT0,
                                              unsigned short* __restrict__ oZ3, unsigned short* __restrict__ oZ2,
                                              unsigned short* __restrict__ oZ1, unsigned short* __restrict__ oZ0,
                                              int N, int E, int EPC, int Gp1) {
    __shared__ __align__(16) unsigned short As[64 * 168];
    __shared__ __align__(16) unsigned short Bs[128 * 168];
    const int bid = blockIdx.x;

    // phase 1: atomic chunk (issue early; deg is fire-and-forget, rank waits for return)
    {
        int e0 = bid * EPC;
        int e1 = e0 + EPC;
        if (e1 > E) e1 = E;
        for (int e = e0 + threadIdx.x; e < e1; e += 256) {
            int s = src[e], d = dst[e];
            float w = (s == d) ? 0.f : ew[e];
            atomicAdd(&deg[s], w);
            rank[e] = (unsigned char)atomicAdd(&cnt[d], 1);
        }
    }

    // phase 2: layer-0 pair GEMM tile (fused concat from f32 x|pe)
    int gemm_id = bid;
    int P = (gemm_id < Gp1) ? 0 : 1;
    int sub = gemm_id - P * Gp1;
    if (sub >= Gp1) return;
    int bx = sub >> 1, bn = sub & 1;
    const unsigned short* Bta = AT0 + (size_t)(3 - 2 * P) * 128 * 160;
    const unsigned short* Btb = AT0 + (size_t)(2 - 2 * P) * 128 * 160;
    unsigned short* outA = (P == 0) ? oZ3 : oZ1;
    unsigned short* outB = (P == 0) ? oZ2 : oZ0;
    gemm_pair_body<160, 1>(nullptr, x, pe, Bta, Btb, outA, outB, N, bx, bn, As, Bs);
}

// ---------------- heads GEMM: [mu|logvar](f32) = h(bf16) @ ATH^T + bias ----------------

__global__ __launch_bounds__(256) void k_gemm_heads(const unsigned short* __restrict__ Abf,
                                                    const unsigned short* __restrict__ Bt,
                                                    float* __restrict__ out,
                                                    const float* __restrict__ bmu, const float* __restrict__ blv,
                                                    int N) {
    constexpr int KPAD = 128;
    constexpr int LP = KPAD + 8;
    __shared__ __align__(16) unsigned short As[128 * LP];
    __shared__ __align__(16) unsigned short Bs[64 * LP];
    const int tid = threadIdx.x;
    const int row0 = blockIdx.x * 128;
    const int bn = blockIdx.y;

    {
        constexpr int TOT = 128 * KPAD;
        for (int c = tid * 8; c < TOT; c += 256 * 8) {
            int r = c / KPAD;
            int k = c - r * KPAD;
            int gr = row0 + r;
            if (gr > N - 1) gr = N - 1;
            u16x8 v = *reinterpret_cast<const u16x8*>(&Abf[(size_t)gr * KPAD + k]);
            *reinterpret_cast<u16x8*>(&As[r * LP + k]) = v;
        }
    }
    {
        constexpr int TOT = 64 * KPAD;
        for (int c = tid * 8; c < TOT; c += 256 * 8) {
            int r = c / KPAD;
            int k = c - r * KPAD;
            u16x8 v = *reinterpret_cast<const u16x8*>(&Bt[(size_t)(bn * 64 + r) * KPAD + k]);
            *reinterpret_cast<u16x8*>(&Bs[r * LP + k]) = v;
        }
    }
    __syncthreads();

    const int wave = tid >> 6, lane = tid & 63;
    const int wm = wave >> 1, wn = wave & 1;
    const int lr = lane & 15, lg = lane >> 4;

    f32x4 acc[4][2];
#pragma unroll
    for (int i = 0; i < 4; i++)
#pragma unroll
        for (int j = 0; j < 2; j++) acc[i][j] = (f32x4){0.f, 0.f, 0.f, 0.f};

    asm volatile("s_nop 7"
                 : "+v"(acc[0][0]), "+v"(acc[0][1]), "+v"(acc[1][0]), "+v"(acc[1][1]),
                   "+v"(acc[2][0]), "+v"(acc[2][1]), "+v"(acc[3][0]), "+v"(acc[3][1]));

#pragma unroll
    for (int ks = 0; ks < KPAD / 32; ks++) {
        u16x8 a[4], b[2];
#pragma unroll
        for (int fm = 0; fm < 4; fm++)
            a[fm] = *reinterpret_cast<const u16x8*>(&As[(wm * 64 + fm * 16 + lr) * LP + ks * 32 + lg * 8]);
#pragma unroll
        for (int fn = 0; fn < 2; fn++)
            b[fn] = *reinterpret_cast<const u16x8*>(&Bs[(wn * 32 + fn * 16 + lr) * LP + ks * 32 + lg * 8]);
#pragma unroll
        for (int fm = 0; fm < 4; fm++)
#pragma unroll
            for (int fn = 0; fn < 2; fn++) mfma16(acc[fm][fn], a[fm], b[fn]);
    }

    asm volatile("s_nop 7\n\ts_nop 7\n\ts_nop 7"
                 : "+v"(acc[0][0]), "+v"(acc[0][1]), "+v"(acc[1][0]), "+v"(acc[1][1]),
                   "+v"(acc[2][0]), "+v"(acc[2][1]), "+v"(acc[3][0]), "+v"(acc[3][1]));

#pragma unroll
    for (int fm = 0; fm < 4; fm++)
#pragma unroll
        for (int fn = 0; fn < 2; fn++)
#pragma unroll
            for (int i = 0; i < 4; i++) {
                int r = row0 + wm * 64 + fm * 16 + lg * 4 + i;
                if (r < N) {
                    int c = bn * 64 + wn * 32 + fn * 16 + lr;
                    if (c < 64) out[(size_t)r * 64 + c] = acc[fm][fn][i] + bmu[c];
                    else out[(size_t)N * 64 + (size_t)r * 64 + (c - 64)] = acc[fm][fn][i] + blv[c - 64];
                }
            }
}

// ---------------- sparse prop: tout = [relu](z + P*tin [+ bias])  — all bf16, fp32 accum ----------------

template <int MODE>  // 0: plain ; 1: + bias, relu
__global__ __launch_bounds__(256) void k_prop(const unsigned int* __restrict__ tin,
                                              const unsigned int* __restrict__ z,
                                              unsigned int* __restrict__ tout,
                                              const float* __restrict__ bias,
                                              const int* __restrict__ rowp,
                                              const long long* __restrict__ pack,
                                              int N, int E) {
    int wave = threadIdx.x >> 6, lane = threadIdx.x & 63;
    int node = blockIdx.x * 4 + wave;
    if (node >= N) return;
    int beg = rowp[node];
    int end = (node == N - 1) ? E : rowp[node + 1];
    float ax = 0.f, ay = 0.f;
    int e = beg;
    for (; e + 3 < end; e += 4) {
        long long q0 = __builtin_nontemporal_load(pack + e);
        long long q1 = __builtin_nontemporal_load(pack + e + 1);
        long long q2 = __builtin_nontemporal_load(pack + e + 2);
        long long q3 = __builtin_nontemporal_load(pack + e + 3);
        unsigned int v0 = tin[(size_t)(unsigned int)q0 * 64 + lane];
        unsigned int v1 = tin[(size_t)(unsigned int)q1 * 64 + lane];
        unsigned int v2 = tin[(size_t)(unsigned int)q2 * 64 + lane];
        unsigned int v3 = tin[(size_t)(unsigned int)q3 * 64 + lane];
        float w0 = __uint_as_float((unsigned int)((unsigned long long)q0 >> 32));
        float w1 = __uint_as_float((unsigned int)((unsigned long long)q1 >> 32));
        float w2 = __uint_as_float((unsigned int)((unsigned long long)q2 >> 32));
        float w3 = __uint_as_float((unsigned int)((unsigned long long)q3 >> 32));
        ax = fmaf(w0, __uint_as_float(v0 << 16), ax);
        ay = fmaf(w0, __uint_as_float(v0 & 0xffff0000u), ay);
        ax = fmaf(w1, __uint_as_float(v1 << 16), ax);
        ay = fmaf(w1, __uint_as_float(v1 & 0xffff0000u), ay);
        ax = fmaf(w2, __uint_as_float(v2 << 16), ax);
        ay = fmaf(w2, __uint_as_float(v2 & 0xffff0000u), ay);
        ax = fmaf(w3, __uint_as_float(v3 << 16), ax);
        ay = fmaf(w3, __uint_as_float(v3 & 0xffff0000u), ay);
    }
    for (; e < end; e++) {
        long long q0 = __builtin_nontemporal_load(pack + e);
        unsigned int v0 = tin[(size_t)(unsigned int)q0 * 64 + lane];
        float w0 = __uint_as_float((unsigned int)((unsigned long long)q0 >> 32));
        ax = fmaf(w0, __uint_as_float(v0 << 16), ax);
        ay = fmaf(w0, __uint_as_float(v0 & 0xffff0000u), ay);
    }
    unsigned int zv = __builtin_nontemporal_load(z + (size_t)node * 64 + lane);
    float rx = __uint_as_float(zv << 16) + ax;
    float ry = __uint_as_float(zv & 0xffff0000u) + ay;
    if (MODE == 1) {
        rx = fmaxf(rx + bias[lane * 2], 0.f);
        ry = fmaxf(ry + bias[lane * 2 + 1], 0.f);
    }
    unsigned int lo = f2bf(rx), hi = f2bf(ry);
    tout[(size_t)node * 64 + lane] = lo | (hi << 16);
}

// ---------------- launch ----------------

extern "C" void kernel_launch(void* const* d_in, const int* in_sizes, int n_in,
                              void* d_out, int out_size, void* d_ws, size_t ws_size,
                              hipStream_t stream) {
    const float* x   = (const float*)d_in[0];
    const int*   ei  = (const int*)d_in[1];
    const float* pe  = (const float*)d_in[2];
    const float* ew  = (const float*)d_in[3];
    const float* W0  = (const float*)d_in[4];
    const float* b0  = (const float*)d_in[5];
    const float* W1  = (const float*)d_in[6];
    const float* b1  = (const float*)d_in[7];
    const float* Wmu = (const float*)d_in[8];
    const float* bmu = (const float*)d_in[9];
    const float* Wlv = (const float*)d_in[10];
    const float* blv = (const float*)d_in[11];

    const int N = in_sizes[0] / 128;
    const int E = in_sizes[3];
    const int* src = ei;
    const int* dst = ei + E;

    char* ws = (char*)d_ws;
    size_t off = 0;
    auto alloc = [&](size_t bytes) {
        size_t o = off;
        off += (bytes + 1023) & ~(size_t)1023;
        return o;
    };
    float* deg = (float*)(ws + alloc(4 * (size_t)N));   // becomes dis in-place
    int* cnt   = (int*)(ws + alloc(4 * (size_t)N));
    size_t zero_bytes = off;                            // memset deg+cnt
    unsigned char* rank = (unsigned char*)(ws + alloc((size_t)E));
    int* rowp  = (int*)(ws + alloc(4 * (size_t)N));
    int* bsum  = (int*)(ws + alloc(4 * 128));
    unsigned short* AT0 = (unsigned short*)(ws + alloc(2 * 4 * 128 * 160));
    unsigned short* AT1 = (unsigned short*)(ws + alloc(2 * 4 * 128 * 128));
    unsigned short* ATH = (unsigned short*)(ws + alloc(2 * 128 * 128));
    int2* pack = (int2*)(ws + alloc(8 * (size_t)E));
    unsigned int* B1 = (unsigned int*)(ws + alloc(2 * (size_t)N * 128));
    unsigned int* B2 = (unsigned int*)(ws + alloc(2 * (size_t)N * 128));
    unsigned int* B3 = (unsigned int*)(ws + alloc(2 * (size_t)N * 128));
    unsigned int* B4 = (unsigned int*)(ws + alloc(2 * (size_t)N * 128));
    unsigned int* B5 = (unsigned int*)(ws + alloc(2 * (size_t)N * 128));

    hipMemsetAsync(ws, 0, zero_bytes, stream);

    dim3 b256(256);
    // weight prep (K1's gemm blocks read AT0)
    k_combine<<<dim3((4 * 128 * 160 + 255) / 256), b256, 0, stream>>>(W0, AT0, 144, 160);
    k_combine<<<dim3((4 * 128 * 128 + 255) / 256), b256, 0, stream>>>(W1, AT1, 128, 128);
    k_headsT<<<dim3((128 * 128 + 255) / 256), b256, 0, stream>>>(Wmu, Wlv, ATH);

    // K1: every block = edge-chunk atomics then a layer-0 pair-GEMM tile (fused concat)
    int Gp1 = ((N + 63) / 64) * 2;   // tiles per pair
    int total = 2 * Gp1;             // all layer-0 tiles
    int EPC = (E + total - 1) / total;
    k_mega<<<dim3(total), b256, 0, stream>>>(src, dst, ew, deg, cnt, rank, x, pe, AT0,
                                             (unsigned short*)B1, (unsigned short*)B2,
                                             (unsigned short*)B3, (unsigned short*)B4,
                                             N, E, EPC, Gp1);

    k_dis<<<dim3((N + 255) / 256), b256, 0, stream>>>(deg, N);
    int nb = (N + 1023) / 1024;
    k_blocksum<<<dim3(nb), dim3(1024), 0, stream>>>(cnt, bsum, N);
    k_scan_bsum<<<dim3(1), dim3(128), 0, stream>>>(bsum, nb);
    k_scan<<<dim3(nb), dim3(1024), 0, stream>>>(cnt, bsum, rowp, N);
    k_build_csr<<<dim3((E + 511) / 512), b256, 0, stream>>>(src, dst, ew, deg, rowp, rank, pack, E);

    dim3 gg((N + 63) / 64, 2, 2);
    dim3 gh((N + 127) / 128, 2);
    dim3 gp((N + 3) / 4);
    const long long* packll = (const long long*)pack;

    // layer 0 (Horner): B1=Z3 B2=Z2 B3=Z1 B4=Z0 (from K1)
    k_prop<0><<<gp, b256, 0, stream>>>(B1, B2, B5, nullptr, rowp, packll, N, E);   // B5 = Z2 + P Z3
    k_prop<0><<<gp, b256, 0, stream>>>(B5, B3, B1, nullptr, rowp, packll, N, E);   // B1 = Z1 + P B5
    k_prop<1><<<gp, b256, 0, stream>>>(B1, B4, B2, b0, rowp, packll, N, E);        // B2 = h1

    // layer 1: both pairs in one launch
    const unsigned short* h1 = (const unsigned short*)B2;
    k_gemm_pair128<<<gg, b256, 0, stream>>>(h1, AT1,
                                            (unsigned short*)B3, (unsigned short*)B4,
                                            (unsigned short*)B1, (unsigned short*)B5, N);
    k_prop<0><<<gp, b256, 0, stream>>>(B3, B4, B2, nullptr, rowp, packll, N, E);   // B2 = Z2' + P Z3'
    k_prop<0><<<gp, b256, 0, stream>>>(B2, B1, B3, nullptr, rowp, packll, N, E);   // B3 = Z1' + P B2
    k_prop<1><<<gp, b256, 0, stream>>>(B3, B5, B4, b1, rowp, packll, N, E);        // B4 = h2

    // heads
    k_gemm_heads<<<gh, b256, 0, stream>>>((const unsigned short*)B4, ATH, (float*)d_out, bmu, blv, N);
}